// Round 7
// baseline (383.303 us; speedup 1.0000x reference)
//
#include <hip/hip_runtime.h>

#define N_NODES 100000
#define N_EDGES 3200000
#define DIM 128

// hierarchical partition geometry
#define NB_C  98       // coarse buckets: dst>>10 (1024 nodes each)
#define CAP_C 36864    // avg 32653, sigma~181 -> +23 sigma
#define NB_F  1568     // fine buckets: 64 nodes each (NB_C*16)
#define CAP_F 2560     // avg 2041, sigma~45 -> +11 sigma
#define CAP   96       // legacy fallback bucket capacity

// payload u64: w_bits[63:32] | dst&1023 [26:17] | src [16:0]

typedef __attribute__((ext_vector_type(4))) float f32x4;
typedef __attribute__((ext_vector_type(8))) short s16x8;

// ============================ helpers ============================

__device__ __forceinline__ unsigned short f2bf(float f) {   // round-to-nearest-even
    unsigned u = __float_as_uint(f);
    return (unsigned short)((u + 0x7fffu + ((u >> 16) & 1u)) >> 16);
}

// ============================ small utility kernels ============================

__global__ __launch_bounds__(256) void zero_i_kernel(int* __restrict__ p, int n) {
    int i = blockIdx.x * 256 + threadIdx.x;
    if (i < n) p[i] = 0;
}

__global__ __launch_bounds__(256) void zero_f_kernel(float* __restrict__ p, int n) {
    int i = blockIdx.x * 256 + threadIdx.x;
    if (i < n) p[i] = 0.0f;
}

__global__ __launch_bounds__(256) void zero_u64_kernel(unsigned long long* __restrict__ p, int n) {
    int i = blockIdx.x * 256 + threadIdx.x;
    if (i < n) p[i] = 0ull;
}

__global__ __launch_bounds__(256) void zero_f4_kernel(float4* __restrict__ p, int n4) {
    int i = blockIdx.x * 256 + threadIdx.x;
    if (i < n4) p[i] = make_float4(0.f, 0.f, 0.f, 0.f);
}

__global__ __launch_bounds__(256) void dinv_kernel(float* __restrict__ deg) {
    int i = blockIdx.x * 256 + threadIdx.x;
    if (i < N_NODES) deg[i] = rsqrtf(deg[i] + 1.0f);
}

__global__ __launch_bounds__(256) void dinv_packed_kernel(const unsigned long long* __restrict__ packed,
                                                          float* __restrict__ dinv) {
    int i = blockIdx.x * 256 + threadIdx.x;
    if (i < N_NODES) {
        unsigned long long p = packed[i];
        float deg = (float)(p & 0xFFFFFFFFFFull) * (1.0f / 4294967296.0f);
        dinv[i] = rsqrtf(deg + 1.0f);
    }
}

__global__ __launch_bounds__(256) void wt_kernel(const float* __restrict__ W,
                                                 float* __restrict__ Wt) {
    int idx = blockIdx.x * 256 + threadIdx.x;
    int j = idx >> 7, k = idx & 127;
    Wt[k * 128 + j] = W[idx];
}

// ==================== prep: W -> MFMA B-fragment tables (hi/lo bf16) + fills ==
// Split precision: W = Wh + Wl with Wh = bf16(W), Wl = bf16(W - Wh).
// Fragment order for mfma_f32_16x16x32_bf16 B-operand:
//   idx = ((ct*4+ks)*64 + lane)*8 + j ; col = ct*16+(lane&15),
//   k = ks*32+(lane>>4)*8+j ; value = W[col][k]  (B[k][n] = W^T[k][n] = W[n][k])
// grid: [0,64) fragment build (16384 elems); [64,71) zero 1666 fill ints

__global__ __launch_bounds__(256) void prep_kernel(const float* __restrict__ W,
                                                   ushort* __restrict__ wf_hi,
                                                   ushort* __restrict__ wf_lo,
                                                   int* __restrict__ fills) {
    const int b = blockIdx.x;
    const int tid = threadIdx.x;
    if (b < 64) {
        int idx  = b * 256 + tid;           // [0,16384)
        int j    = idx & 7;
        int lane = (idx >> 3) & 63;
        int ks   = (idx >> 9) & 3;
        int ct   = idx >> 11;
        int col  = ct * 16 + (lane & 15);
        int k    = ks * 32 + ((lane >> 4) << 3) + j;
        float w  = W[col * 128 + k];
        unsigned short hb = f2bf(w);
        float rem = w - __uint_as_float((unsigned)hb << 16);
        wf_hi[idx] = hb;
        wf_lo[idx] = f2bf(rem);
    } else {
        int i = (b - 64) * 256 + tid;
        if (i < NB_C + NB_F) fills[i] = 0;
    }
}

// ==================== pass A1: edges -> 98 coarse buckets ====================
// Per-wave histograms (hist[4][98]): removes cross-wave LDS-atomic
// interference; combine step computes per-wave bases via one global atomic.

__global__ __launch_bounds__(256) void partA1_kernel(const int* __restrict__ ei,
                                                     const float* __restrict__ ew,
                                                     int* __restrict__ fill_c,
                                                     unsigned long long* __restrict__ edc) {
    __shared__ int hist[4][NB_C];
    __shared__ int base[4][NB_C];
    const int tid = threadIdx.x;
    const int wave = tid >> 6;
    const int blockbase = blockIdx.x * 4096;
    for (int i = tid; i < 4 * NB_C; i += 256) hist[i / NB_C][i % NB_C] = 0;
    __syncthreads();

    unsigned long long pay[16];
    unsigned meta[16];
#pragma unroll
    for (int i = 0; i < 16; ++i) {
        int e = blockbase + i * 256 + tid;
        meta[i] = 0xFFFFFFFFu;
        if (e < N_EDGES) {
            int src = ei[e];
            int dst = ei[N_EDGES + e];
            float w = ew[e];
            int cb = dst >> 10;
            int pos = atomicAdd(&hist[wave][cb], 1);
            pay[i] = ((unsigned long long)__float_as_uint(w) << 32)
                   | ((unsigned)(dst & 1023) << 17) | (unsigned)src;
            meta[i] = ((unsigned)cb << 16) | (unsigned)pos;
        }
    }
    __syncthreads();
    for (int c = tid; c < NB_C; c += 256) {
        int h0 = hist[0][c], h1 = hist[1][c], h2 = hist[2][c], h3 = hist[3][c];
        int tot = h0 + h1 + h2 + h3;
        int g = (tot > 0) ? atomicAdd(&fill_c[c], tot) : 0;
        base[0][c] = g;
        base[1][c] = g + h0;
        base[2][c] = g + h0 + h1;
        base[3][c] = g + h0 + h1 + h2;
    }
    __syncthreads();
#pragma unroll
    for (int i = 0; i < 16; ++i) {
        if (meta[i] != 0xFFFFFFFFu) {
            int cb = (int)(meta[i] >> 16);
            int pos = base[wave][cb] + (int)(meta[i] & 0xFFFFu);
            if (pos < CAP_C)
                edc[(unsigned)cb * CAP_C + (unsigned)pos] = pay[i];
        }
    }
}

// ==================== pass A2: coarse -> 16 fine sub-buckets each ==============
// 9 slice-blocks per coarse bucket (9*4096 >= CAP_C).
// 64 lanes -> 16 bins is a guaranteed >=4-way LDS-atomic serialization, so
// each wave gets 4 sub-counters per bin (hist[wave][f*4+(lane&3)] -> 64
// sub-bins/wave ~ 1.6-way). Combine: one thread per f does the 16-step prefix.

__global__ __launch_bounds__(256) void partA2_kernel(const int* __restrict__ fill_c,
                                                     const unsigned long long* __restrict__ edc,
                                                     int* __restrict__ fill_f,
                                                     unsigned long long* __restrict__ edf) {
    __shared__ int hist[4][64];
    __shared__ int base[4][64];
    const int tid = threadIdx.x;
    const int wave = tid >> 6;
    const int sub = tid & 3;
    const int cb = blockIdx.x / 9;
    const int lo = (blockIdx.x % 9) * 4096;
    const int cnt_c = min(fill_c[cb], CAP_C);
    const int hi = min(lo + 4096, cnt_c);
    hist[wave][tid & 63] = 0;
    __syncthreads();

    unsigned long long pay[16];
    unsigned meta[16];
#pragma unroll
    for (int i = 0; i < 16; ++i) {
        int idx = lo + i * 256 + tid;
        meta[i] = 0xFFFFFFFFu;
        if (idx < hi) {
            unsigned long long p = edc[(unsigned)cb * CAP_C + (unsigned)idx];
            int f = (int)((p >> 23) & 15);      // dst bits [6,10)
            int bin = f * 4 + sub;
            int pos = atomicAdd(&hist[wave][bin], 1);
            pay[i] = p;
            meta[i] = ((unsigned)bin << 16) | (unsigned)pos;
        }
    }
    __syncthreads();
    if (tid < 16) {
        // prefix over the 16 (wave,sub) counters of bin-group f = tid
        int run = 0;
#pragma unroll
        for (int w = 0; w < 4; ++w)
#pragma unroll
            for (int s = 0; s < 4; ++s) {
                base[w][tid * 4 + s] = run;
                run += hist[w][tid * 4 + s];
            }
        int g = (run > 0) ? atomicAdd(&fill_f[cb * 16 + tid], run) : 0;
#pragma unroll
        for (int w = 0; w < 4; ++w)
#pragma unroll
            for (int s = 0; s < 4; ++s)
                base[w][tid * 4 + s] += g;
    }
    __syncthreads();
#pragma unroll
    for (int i = 0; i < 16; ++i) {
        if (meta[i] != 0xFFFFFFFFu) {
            int bin = (int)(meta[i] >> 16);
            int f = bin >> 2;
            int pos = base[wave][bin] + (int)(meta[i] & 0xFFFFu);
            if (pos < CAP_F)
                edf[((unsigned)(cb * 16 + f)) * CAP_F + (unsigned)pos] = pay[i];
        }
    }
}

// ==================== pass B: in-place CSR compaction + degree/dinv ===========
// one block per fine bucket (64 nodes); scatter window 20 KB = L2-resident.
// STATIC-INDEXED pay/meta (rule #20: the old dynamically-indexed pay[m]
// went to scratch -> localMem traffic). Per-wave histograms + deg bins
// (hist[4][64], degs[4][64]) remove cross-wave LDS-atomic interference.
// ALSO converts its 64 owned rows of x to bf16 pre-scaled by dinv.

__global__ __launch_bounds__(256) void partB_kernel(const int* __restrict__ fill_f,
                                                    unsigned long long* __restrict__ edf,
                                                    float* __restrict__ dinv,
                                                    int* __restrict__ row_start,
                                                    int* __restrict__ row_cnt,
                                                    const float4* __restrict__ x4,
                                                    ushort4* __restrict__ xh4) {
    __shared__ int hist[4][64];
    __shared__ float degs[4][64];
    __shared__ int pref[64];
    __shared__ int wbase[4][64];
    __shared__ float dinv_s[64];
    const int tid = threadIdx.x;
    const int wave = tid >> 6;
    const int lane = tid & 63;
    const int fb = blockIdx.x;
    const int node_base = fb * 64;
    const int cnt = min(fill_f[fb], CAP_F);
    hist[wave][lane] = 0;
    degs[wave][lane] = 0.0f;
    __syncthreads();

    unsigned long long pay[10];
    unsigned meta[10];
#pragma unroll
    for (int it = 0; it < 10; ++it) {           // CAP_F/256 = 10, static indices
        int idx = it * 256 + tid;
        meta[it] = 0xFFFFFFFFu;
        if (idx < cnt) {
            unsigned long long p = edf[(unsigned)fb * CAP_F + (unsigned)idx];
            int dl = (int)((p >> 17) & 63);
            int pos = atomicAdd(&hist[wave][dl], 1);
            atomicAdd(&degs[wave][dl], __uint_as_float((unsigned)(p >> 32)));
            pay[it] = p;
            meta[it] = ((unsigned)dl << 16) | (unsigned)pos;
        }
    }
    __syncthreads();
    if (tid < 64) {
        int h0 = hist[0][tid], h1 = hist[1][tid], h2 = hist[2][tid], h3 = hist[3][tid];
        wbase[0][tid] = 0;
        wbase[1][tid] = h0;
        wbase[2][tid] = h0 + h1;
        wbase[3][tid] = h0 + h1 + h2;
        hist[0][tid] = h0 + h1 + h2 + h3;       // total per dl
        degs[0][tid] = degs[0][tid] + degs[1][tid] + degs[2][tid] + degs[3][tid];
    }
    __syncthreads();
    if (tid == 0) {
        int run = 0;
#pragma unroll
        for (int n = 0; n < 64; ++n) { pref[n] = run; run += hist[0][n]; }
    }
    __syncthreads();
    if (tid < 64) {
        int node = node_base + tid;
        if (node < N_NODES) {
            float dv = rsqrtf(degs[0][tid] + 1.0f);
            dinv[node] = dv;
            dinv_s[tid] = dv;
            row_start[node] = fb * CAP_F + pref[tid];
            row_cnt[node] = hist[0][tid];
        }
    }
    __syncthreads();
    // all reads completed before the barriers above -> safe in-place compaction
#pragma unroll
    for (int it = 0; it < 10; ++it) {
        if (meta[it] != 0xFFFFFFFFu) {
            int dl = (int)(meta[it] >> 16);
            int pos = pref[dl] + wbase[wave][dl] + (int)(meta[it] & 0xFFFFu);
            edf[(unsigned)fb * CAP_F + (unsigned)pos] = pay[it];
        }
    }
    // fused xscale: xh[node,:] = bf16(x[node,:] * dinv[node]) for owned rows
#pragma unroll
    for (int i = 0; i < 8; ++i) {
        int idx = i * 256 + tid;            // [0,2048): 64 rows x 32 float4
        int r = idx >> 5;
        int node = node_base + r;
        if (node < N_NODES) {
            float dv = dinv_s[r];
            float4 v = x4[(unsigned)node * 32u + (unsigned)(idx & 31)];
            ushort4 h;
            h.x = f2bf(v.x * dv); h.y = f2bf(v.y * dv);
            h.z = f2bf(v.z * dv); h.w = f2bf(v.w * dv);
            xh4[(unsigned)node * 32u + (unsigned)(idx & 31)] = h;
        }
    }
}

// ==================== gather over exact CSR runs, bf16 x (pre-scaled) ========
// R1 version, byte-for-byte (107 us verified): node-per-wave, register
// accumulators, 8-deep ping-pong prefetch pipeline. MSHR*latency-bound plateau.

__global__ __launch_bounds__(256) void gatherc_kernel(const int* __restrict__ row_start,
                                                      const int* __restrict__ row_cnt,
                                                      const unsigned long long* __restrict__ edf,
                                                      const float* __restrict__ dinv,
                                                      const unsigned* __restrict__ xh,
                                                      float2* __restrict__ agg2) {
    const int lane = threadIdx.x & 63;
    const int node = blockIdx.x * 4 + (threadIdx.x >> 6);

    const int cnt = row_cnt[node];
    const int start = row_start[node];
    float ax0 = 0.f, ay0 = 0.f, ax1 = 0.f, ay1 = 0.f;   // 4 independent FMA chains

    for (int b = 0; b < cnt; b += 64) {
        int idx = b + lane;
        const bool valid = idx < cnt;
        if (!valid) idx = cnt - 1;                      // clamp: cached re-read
        unsigned long long p = edf[(unsigned)(start + idx)];
        int msrc = (int)(p & 0x1FFFFull);
        float mw = valid ? __uint_as_float((unsigned)(p >> 32)) : 0.0f;  // zero-pad
        const int mcnt = min(64, cnt - b);
        const int ng = (mcnt + 7) >> 3;                 // 8-edge groups (padded)

        unsigned va[8], vb[8];

#define PREF(buf, JB)                                                          \
        _Pragma("unroll")                                                      \
        for (int j = 0; j < 8; ++j) {                                          \
            int s = __builtin_amdgcn_readlane(msrc, (JB) + j);                 \
            buf[j] = xh[(unsigned)s * 64u + (unsigned)lane];                   \
        }
#define CONSUME(buf, JB)                                                       \
        _Pragma("unroll")                                                      \
        for (int j = 0; j < 8; ++j) {                                          \
            float w = __int_as_float(                                          \
                __builtin_amdgcn_readlane(__float_as_int(mw), (JB) + j));      \
            if (j & 1) {                                                       \
                ax1 = fmaf(__uint_as_float(buf[j] << 16), w, ax1);             \
                ay1 = fmaf(__uint_as_float(buf[j] & 0xffff0000u), w, ay1);     \
            } else {                                                           \
                ax0 = fmaf(__uint_as_float(buf[j] << 16), w, ax0);             \
                ay0 = fmaf(__uint_as_float(buf[j] & 0xffff0000u), w, ay0);     \
            }                                                                  \
        }

        PREF(va, 0);
        int g = 0;
        for (; g + 2 < ng; g += 2) {
            PREF(vb, (g + 1) * 8);      // issue next group while consuming va
            CONSUME(va, g * 8);
            PREF(va, (g + 2) * 8);      // ping-pong back
            CONSUME(vb, (g + 1) * 8);
        }
        if (g + 1 < ng) {               // two groups remain
            PREF(vb, (g + 1) * 8);
            CONSUME(va, g * 8);
            CONSUME(vb, (g + 1) * 8);
        } else {                        // one group remains
            CONSUME(va, g * 8);
        }
#undef PREF
#undef CONSUME
    }

    float di = dinv[node];
    agg2[(unsigned)node * 64u + lane] = make_float2((ax0 + ax1) * di, (ay0 + ay1) * di);
}

// ==================== fallback kernels (f32 bucket / CSR / scatter) ===========

__global__ __launch_bounds__(256) void bucket_f32_kernel(const int* __restrict__ ei,
                                                         const float* __restrict__ ew,
                                                         unsigned long long* __restrict__ packed,
                                                         int2* __restrict__ ed) {
    int e = blockIdx.x * 256 + threadIdx.x;
    int src = ei[e];
    int dst = ei[N_EDGES + e];
    float w = ew[e];
    unsigned long long inc = (1ull << 40) | (unsigned long long)(w * 4294967296.0f);
    unsigned long long old = atomicAdd(&packed[dst], inc);
    unsigned slot = (unsigned)(old >> 40);
    if (slot < CAP) {
        ed[(unsigned)dst * CAP + slot] = make_int2(src, __float_as_int(w));
    }
}

__global__ __launch_bounds__(256) void gatherb_f32_kernel(const unsigned long long* __restrict__ packed,
                                                          const int2* __restrict__ ed,
                                                          const float* __restrict__ dinv,
                                                          const float2* __restrict__ x2,
                                                          float2* __restrict__ agg2) {
    const int wave = threadIdx.x >> 6;
    const int lane = threadIdx.x & 63;
    const int node = blockIdx.x * 4 + wave;

    int cnt = (int)(packed[node] >> 40);
    cnt = min(cnt, CAP);
    const unsigned base = (unsigned)node * CAP;
    float2 acc = make_float2(0.f, 0.f);

    for (int b = 0; b < cnt; b += 64) {
        int idx = b + lane;
        if (idx >= cnt) idx = cnt - 1;
        int2 my = ed[base + idx];
        float wmy = __int_as_float(my.y) * dinv[my.x];
        int m = min(64, cnt - b);
#pragma unroll 8
        for (int j = 0; j < m; ++j) {
            int s = __builtin_amdgcn_readlane(my.x, j);
            float w = __int_as_float(__builtin_amdgcn_readlane(__float_as_int(wmy), j));
            float2 v = x2[(unsigned)s * 64u + lane];
            acc.x = fmaf(v.x, w, acc.x); acc.y = fmaf(v.y, w, acc.y);
        }
    }
    float di = dinv[node];
    acc.x *= di; acc.y *= di;
    agg2[(unsigned)node * 64u + lane] = acc;
}

__global__ __launch_bounds__(256) void count_deg_kernel(const int* __restrict__ ei,
                                                        const float* __restrict__ ew,
                                                        int* __restrict__ count,
                                                        float* __restrict__ deg) {
    int e = blockIdx.x * 256 + threadIdx.x;
    int dst = ei[N_EDGES + e];
    atomicAdd(&count[dst], 1);
    atomicAdd(&deg[dst], ew[e]);
}

__global__ __launch_bounds__(256) void scatter_kernel(const int* __restrict__ ei,
                                                      const float* __restrict__ ew,
                                                      const float* __restrict__ dinv,
                                                      const float4* __restrict__ x4,
                                                      float* __restrict__ agg) {
    unsigned gid = blockIdx.x * 256u + threadIdx.x;
    unsigned e  = gid >> 5;
    unsigned f4 = gid & 31u;
    int src = ei[e];
    int dst = ei[N_EDGES + e];
    float w = dinv[src] * ew[e] * dinv[dst];
    float4 v = x4[(unsigned)src * 32u + f4];
    float* o = agg + ((unsigned)dst * 128u + f4 * 4u);
    atomicAdd(o + 0, v.x * w);
    atomicAdd(o + 1, v.y * w);
    atomicAdd(o + 2, v.z * w);
    atomicAdd(o + 3, v.w * w);
}

// ============================ final: split-bf16 MFMA GEMM + epilogue ==========
// out[i,:] = relu( (agg[i,:] + x[i,:]*dinv[i]^2) @ W^T + bias ) + x[i,:]
// A = Ah+Al, W = Wh+Wl (bf16 splits); A@W ~= Ah@Wh + Ah@Wl + Al@Wh
// (error ~2^-17 rel, keeps f32-grade absmax). UNCHANGED this round.

__global__ __launch_bounds__(256) void final_mfma_kernel(const float* __restrict__ agg_in,
                                                         const float* __restrict__ x,
                                                         const float* __restrict__ bias,
                                                         const float* __restrict__ dinv,
                                                         const ushort* __restrict__ wf_hi,
                                                         const ushort* __restrict__ wf_lo,
                                                         float* __restrict__ out) {
    __shared__ ushort sh_hi[16384];
    __shared__ ushort sh_lo[16384];
    const int tid = threadIdx.x;
    {
        const float4* sh4 = (const float4*)wf_hi;
        const float4* sl4 = (const float4*)wf_lo;
        float4* dh = (float4*)sh_hi;
        float4* dl = (float4*)sh_lo;
#pragma unroll
        for (int i = 0; i < 8; ++i) {
            dh[i * 256 + tid] = sh4[i * 256 + tid];
            dl[i * 256 + tid] = sl4[i * 256 + tid];
        }
    }
    __syncthreads();

    const int wave = tid >> 6;
    const int lane = tid & 63;
    const int r0 = blockIdx.x * 64 + wave * 16;
    const int mrow = lane & 15;          // A row within tile
    const int kg = lane >> 4;            // k-group
    const int arow = min(r0 + mrow, N_NODES - 1);   // clamped (tail block)
    const float di = dinv[arow];
    const float di2 = di * di;

    // A-fragments: lane holds 8 k-contiguous elems at k = ks*32 + kg*8 + j
    s16x8 ah[4], al[4];
#pragma unroll
    for (int ks = 0; ks < 4; ++ks) {
        const float* ap = agg_in + (unsigned)arow * 128u + ks * 32 + kg * 8;
        const float* xp = x      + (unsigned)arow * 128u + ks * 32 + kg * 8;
        float4 a0 = *(const float4*)ap;
        float4 a1 = *(const float4*)(ap + 4);
        float4 x0 = *(const float4*)xp;
        float4 x1 = *(const float4*)(xp + 4);
        float v[8] = {a0.x + x0.x * di2, a0.y + x0.y * di2,
                      a0.z + x0.z * di2, a0.w + x0.w * di2,
                      a1.x + x1.x * di2, a1.y + x1.y * di2,
                      a1.z + x1.z * di2, a1.w + x1.w * di2};
        s16x8 h, l;
#pragma unroll
        for (int j = 0; j < 8; ++j) {
            unsigned short hb = f2bf(v[j]);
            h[j] = (short)hb;
            l[j] = (short)f2bf(v[j] - __uint_as_float((unsigned)hb << 16));
        }
        ah[ks] = h; al[ks] = l;
    }

#pragma unroll
    for (int ct = 0; ct < 8; ++ct) {
        f32x4 acc = {0.f, 0.f, 0.f, 0.f};
#pragma unroll
        for (int ks = 0; ks < 4; ++ks) {
            const int fo = ((ct * 4 + ks) * 64 + lane) * 8;
            s16x8 bh = *(const s16x8*)&sh_hi[fo];
            s16x8 bl = *(const s16x8*)&sh_lo[fo];
            acc = __builtin_amdgcn_mfma_f32_16x16x32_bf16(ah[ks], bh, acc, 0, 0, 0);
            acc = __builtin_amdgcn_mfma_f32_16x16x32_bf16(ah[ks], bl, acc, 0, 0, 0);
            acc = __builtin_amdgcn_mfma_f32_16x16x32_bf16(al[ks], bh, acc, 0, 0, 0);
        }
        // C/D layout (m89-verified): col = lane&15, row = (lane>>4)*4 + reg
        const int col = ct * 16 + mrow;
        const float bv = bias[col];
#pragma unroll
        for (int v = 0; v < 4; ++v) {
            const int row = r0 + kg * 4 + v;
            if (row < N_NODES) {
                float o = fmaxf(acc[v] + bv, 0.f) + x[(unsigned)row * 128u + col];
                out[(unsigned)row * 128u + col] = o;
            }
        }
    }
}

// ============================ legacy vector final (fallback paths) ============

__global__ __launch_bounds__(256) void final_kernel(const float* __restrict__ agg_in,
                                                    const float* __restrict__ x,
                                                    const float* __restrict__ bias,
                                                    const float* __restrict__ dinv,
                                                    const float* __restrict__ Wt,
                                                    float* __restrict__ out) {
    __shared__ float sh_wt[16384];
    const int tid = threadIdx.x;
    {
        const float4* s4 = (const float4*)Wt;
        float4* d4 = (float4*)sh_wt;
#pragma unroll
        for (int i = 0; i < 16; ++i) d4[i * 256 + tid] = s4[i * 256 + tid];
    }
    __syncthreads();

    const int wave = tid >> 6;
    const int lane = tid & 63;
    const int rowbase = blockIdx.x * 32 + wave * 8;

    float areg[16];
#pragma unroll
    for (int r = 0; r < 8; ++r) {
        int row = rowbase + r;
        float di = dinv[row];
        float di2 = di * di;
        int base = row * 128;
        areg[2 * r]     = agg_in[base + lane]      + x[base + lane]      * di2;
        areg[2 * r + 1] = agg_in[base + 64 + lane] + x[base + 64 + lane] * di2;
    }

    float acc0[8], acc1[8];
#pragma unroll
    for (int r = 0; r < 8; ++r) { acc0[r] = 0.f; acc1[r] = 0.f; }

    const float2* wt2 = (const float2*)sh_wt;

#pragma unroll
    for (int kh = 0; kh < 2; ++kh) {
#pragma unroll 16
        for (int kk = 0; kk < 64; ++kk) {
            int k = kh * 64 + kk;
            float2 w = wt2[k * 64 + lane];
#pragma unroll
            for (int r = 0; r < 8; ++r) {
                float ak = __uint_as_float(
                    __builtin_amdgcn_readlane(__float_as_uint(areg[2 * r + kh]), kk));
                acc0[r] = fmaf(ak, w.x, acc0[r]);
                acc1[r] = fmaf(ak, w.y, acc1[r]);
            }
        }
    }

    float2 b = ((const float2*)bias)[lane];
#pragma unroll
    for (int r = 0; r < 8; ++r) {
        int row = rowbase + r;
        float2 xr = ((const float2*)x)[row * 64 + lane];
        float v0 = fmaxf(acc0[r] + b.x, 0.f) + xr.x;
        float v1 = fmaxf(acc1[r] + b.y, 0.f) + xr.y;
        ((float2*)out)[row * 64 + lane] = make_float2(v0, v1);
    }
}

// ===============================================================================

extern "C" void kernel_launch(void* const* d_in, const int* in_sizes, int n_in,
                              void* d_out, int out_size, void* d_ws, size_t ws_size,
                              hipStream_t stream) {
    const float* x    = (const float*)d_in[0];
    const float* W    = (const float*)d_in[1];
    const float* bias = (const float*)d_in[2];
    const float* ew   = (const float*)d_in[3];
    const int*   ei   = (const int*)d_in[4];
    float* out = (float*)d_out;
    char* ws = (char*)d_ws;

    // ---------- primary layout (hierarchical partition) ----------
    // xh bf16[N*128]       [0, 25600000)
    // Wfrag hi/lo ushort   [25600000, 25665536)
    // dinv f32[N]          [25665536, 26065536)
    // row_start int[N]     [26065536, 26465536)
    // row_cnt int[N]       [26465536, 26865536)
    // fill_c int[98]       [26865536, ...) contiguous with fill_f int[1568]
    // edc u64[98*36864]    [26872256, 55773632)
    // edf u64[1568*2560]   [55773632, 87886272)
    unsigned short* xhA  = (unsigned short*)ws;
    ushort* wfhi     = (ushort*)(ws + 25600000);
    ushort* wflo     = wfhi + 16384;
    float* dinvA     = (float*)(ws + 25665536);
    int*   row_start = (int*)  (ws + 26065536);
    int*   row_cnt   = (int*)  (ws + 26465536);
    int*   fill_c    = (int*)  (ws + 26865536);
    int*   fill_f    = fill_c + NB_C;
    unsigned long long* edc = (unsigned long long*)(ws + 26872256);
    unsigned long long* edf = (unsigned long long*)(ws + 55773632);
    const size_t WS_PART = 87886272ull;

    // ---------- fallback layout (round-3 bucket) ----------
    unsigned long long* packed = (unsigned long long*)ws;
    float* dinvB = (float*)(ws + 800000);
    float* WtB   = (float*)(ws + 1200000);
    int2*  edB   = (int2*)(ws + 1265536);
    const size_t WS_BUCKET = 1265536ull + (size_t)N_NODES * CAP * 8ull;   // ~78.1 MB

    if (ws_size >= WS_PART) {
        prep_kernel<<<71, 256, 0, stream>>>(W, wfhi, wflo, fill_c);
        partA1_kernel<<<(N_EDGES + 4095) / 4096, 256, 0, stream>>>(ei, ew, fill_c, edc);
        partA2_kernel<<<NB_C * 9, 256, 0, stream>>>(fill_c, edc, fill_f, edf);
        partB_kernel<<<NB_F, 256, 0, stream>>>(fill_f, edf, dinvA, row_start, row_cnt,
                                               (const float4*)x, (ushort4*)xhA);
        gatherc_kernel<<<N_NODES / 4, 256, 0, stream>>>(row_start, row_cnt, edf, dinvA,
                                                        (const unsigned*)xhA, (float2*)out);
        final_mfma_kernel<<<(N_NODES + 63) / 64, 256, 0, stream>>>(out, x, bias, dinvA,
                                                                   wfhi, wflo, out);
    } else if (ws_size >= WS_BUCKET) {
        zero_u64_kernel<<<(N_NODES + 255) / 256, 256, 0, stream>>>(packed, N_NODES);
        wt_kernel<<<64, 256, 0, stream>>>(W, WtB);
        bucket_f32_kernel<<<N_EDGES / 256, 256, 0, stream>>>(ei, ew, packed, edB);
        dinv_packed_kernel<<<(N_NODES + 255) / 256, 256, 0, stream>>>(packed, dinvB);
        gatherb_f32_kernel<<<N_NODES / 4, 256, 0, stream>>>(packed, edB, dinvB,
                                                            (const float2*)x, (float2*)out);
        final_kernel<<<N_NODES / 32, 256, 0, stream>>>(out, x, bias, dinvB, WtB, out);
    } else {
        float* deg   = (float*)(ws);
        float* Wt    = (float*)(ws + 400000);
        int*   count = (int*)  (ws + 465536);
        zero_f_kernel<<<(N_NODES + 255) / 256, 256, 0, stream>>>(deg, N_NODES);
        zero_i_kernel<<<(N_NODES + 255) / 256, 256, 0, stream>>>(count, N_NODES);
        wt_kernel<<<64, 256, 0, stream>>>(W, Wt);
        zero_f4_kernel<<<(N_NODES * DIM / 4) / 256, 256, 0, stream>>>((float4*)out,
                                                                      N_NODES * DIM / 4);
        count_deg_kernel<<<N_EDGES / 256, 256, 0, stream>>>(ei, ew, count, deg);
        dinv_kernel<<<(N_NODES + 255) / 256, 256, 0, stream>>>(deg);
        scatter_kernel<<<(N_EDGES / 256) * 32, 256, 0, stream>>>(ei, ew, deg,
                                                                 (const float4*)x, out);
        final_kernel<<<N_NODES / 32, 256, 0, stream>>>(out, x, bias, deg, Wt, out);
    }
}

// Round 8
// 370.220 us; speedup vs baseline: 1.0353x; 1.0353x over previous
//
#include <hip/hip_runtime.h>

#define N_NODES 100000
#define N_EDGES 3200000
#define DIM 128

// hierarchical partition geometry
#define NB_C  98       // coarse buckets: dst>>10 (1024 nodes each)
#define CAP_C 36864    // avg 32653, sigma~181 -> +23 sigma
#define NB_F  1568     // fine buckets: 64 nodes each (NB_C*16)
#define CAP_F 2560     // avg 2041, sigma~45 -> +11 sigma
#define CAP   96       // legacy fallback bucket capacity

// payload u64: w_bits[63:32] | dst&1023 [26:17] | src [16:0]

typedef __attribute__((ext_vector_type(4))) float f32x4;
typedef __attribute__((ext_vector_type(8))) short s16x8;

// ============================ helpers ============================

__device__ __forceinline__ unsigned short f2bf(float f) {   // round-to-nearest-even
    unsigned u = __float_as_uint(f);
    return (unsigned short)((u + 0x7fffu + ((u >> 16) & 1u)) >> 16);
}

// ============================ small utility kernels ============================

__global__ __launch_bounds__(256) void zero_i_kernel(int* __restrict__ p, int n) {
    int i = blockIdx.x * 256 + threadIdx.x;
    if (i < n) p[i] = 0;
}

__global__ __launch_bounds__(256) void zero_f_kernel(float* __restrict__ p, int n) {
    int i = blockIdx.x * 256 + threadIdx.x;
    if (i < n) p[i] = 0.0f;
}

__global__ __launch_bounds__(256) void zero_u64_kernel(unsigned long long* __restrict__ p, int n) {
    int i = blockIdx.x * 256 + threadIdx.x;
    if (i < n) p[i] = 0ull;
}

__global__ __launch_bounds__(256) void zero_f4_kernel(float4* __restrict__ p, int n4) {
    int i = blockIdx.x * 256 + threadIdx.x;
    if (i < n4) p[i] = make_float4(0.f, 0.f, 0.f, 0.f);
}

__global__ __launch_bounds__(256) void dinv_kernel(float* __restrict__ deg) {
    int i = blockIdx.x * 256 + threadIdx.x;
    if (i < N_NODES) deg[i] = rsqrtf(deg[i] + 1.0f);
}

__global__ __launch_bounds__(256) void dinv_packed_kernel(const unsigned long long* __restrict__ packed,
                                                          float* __restrict__ dinv) {
    int i = blockIdx.x * 256 + threadIdx.x;
    if (i < N_NODES) {
        unsigned long long p = packed[i];
        float deg = (float)(p & 0xFFFFFFFFFFull) * (1.0f / 4294967296.0f);
        dinv[i] = rsqrtf(deg + 1.0f);
    }
}

__global__ __launch_bounds__(256) void wt_kernel(const float* __restrict__ W,
                                                 float* __restrict__ Wt) {
    int idx = blockIdx.x * 256 + threadIdx.x;
    int j = idx >> 7, k = idx & 127;
    Wt[k * 128 + j] = W[idx];
}

// ==================== prep: W -> MFMA B-fragment tables (hi/lo bf16) + fills ==
// Split precision: W = Wh + Wl with Wh = bf16(W), Wl = bf16(W - Wh).
// Fragment order for mfma_f32_16x16x32_bf16 B-operand:
//   idx = ((ct*4+ks)*64 + lane)*8 + j ; col = ct*16+(lane&15),
//   k = ks*32+(lane>>4)*8+j ; value = W[col][k]  (B[k][n] = W^T[k][n] = W[n][k])
// grid: [0,64) fragment build (16384 elems); [64,71) zero 1666 fill ints

__global__ __launch_bounds__(256) void prep_kernel(const float* __restrict__ W,
                                                   ushort* __restrict__ wf_hi,
                                                   ushort* __restrict__ wf_lo,
                                                   int* __restrict__ fills) {
    const int b = blockIdx.x;
    const int tid = threadIdx.x;
    if (b < 64) {
        int idx  = b * 256 + tid;           // [0,16384)
        int j    = idx & 7;
        int lane = (idx >> 3) & 63;
        int ks   = (idx >> 9) & 3;
        int ct   = idx >> 11;
        int col  = ct * 16 + (lane & 15);
        int k    = ks * 32 + ((lane >> 4) << 3) + j;
        float w  = W[col * 128 + k];
        unsigned short hb = f2bf(w);
        float rem = w - __uint_as_float((unsigned)hb << 16);
        wf_hi[idx] = hb;
        wf_lo[idx] = f2bf(rem);
    } else {
        int i = (b - 64) * 256 + tid;
        if (i < NB_C + NB_F) fills[i] = 0;
    }
}

// ==================== pass A1: edges -> 98 coarse buckets (R6 form) ==========

__global__ __launch_bounds__(256) void partA1_kernel(const int* __restrict__ ei,
                                                     const float* __restrict__ ew,
                                                     int* __restrict__ fill_c,
                                                     unsigned long long* __restrict__ edc) {
    __shared__ int hist[NB_C];
    __shared__ int base[NB_C];
    const int tid = threadIdx.x;
    const int blockbase = blockIdx.x * 4096;
    for (int i = tid; i < NB_C; i += 256) hist[i] = 0;
    __syncthreads();

    unsigned long long pay[16];
    unsigned meta[16];
#pragma unroll
    for (int i = 0; i < 16; ++i) {
        int e = blockbase + i * 256 + tid;
        meta[i] = 0xFFFFFFFFu;
        if (e < N_EDGES) {
            int src = ei[e];
            int dst = ei[N_EDGES + e];
            float w = ew[e];
            int cb = dst >> 10;
            int pos = atomicAdd(&hist[cb], 1);
            pay[i] = ((unsigned long long)__float_as_uint(w) << 32)
                   | ((unsigned)(dst & 1023) << 17) | (unsigned)src;
            meta[i] = ((unsigned)cb << 16) | (unsigned)pos;
        }
    }
    __syncthreads();
    for (int c = tid; c < NB_C; c += 256) {
        int cnt = hist[c];
        base[c] = (cnt > 0) ? atomicAdd(&fill_c[c], cnt) : 0;
    }
    __syncthreads();
#pragma unroll
    for (int i = 0; i < 16; ++i) {
        if (meta[i] != 0xFFFFFFFFu) {
            int cb = (int)(meta[i] >> 16);
            int pos = base[cb] + (int)(meta[i] & 0xFFFFu);
            if (pos < CAP_C)
                edc[(unsigned)cb * CAP_C + (unsigned)pos] = pay[i];
        }
    }
}

// ==================== pass A2: coarse -> 16 fine sub-buckets each (R6 form) ===
// 9 slice-blocks per coarse bucket (9*4096 >= CAP_C)

__global__ __launch_bounds__(256) void partA2_kernel(const int* __restrict__ fill_c,
                                                     const unsigned long long* __restrict__ edc,
                                                     int* __restrict__ fill_f,
                                                     unsigned long long* __restrict__ edf) {
    __shared__ int hist[16];
    __shared__ int base[16];
    const int tid = threadIdx.x;
    const int cb = blockIdx.x / 9;
    const int lo = (blockIdx.x % 9) * 4096;
    const int cnt_c = min(fill_c[cb], CAP_C);
    const int hi = min(lo + 4096, cnt_c);
    if (tid < 16) hist[tid] = 0;
    __syncthreads();

    unsigned long long pay[16];
    unsigned meta[16];
#pragma unroll
    for (int i = 0; i < 16; ++i) {
        int idx = lo + i * 256 + tid;
        meta[i] = 0xFFFFFFFFu;
        if (idx < hi) {
            unsigned long long p = edc[(unsigned)cb * CAP_C + (unsigned)idx];
            int f = (int)((p >> 23) & 15);      // dst bits [6,10)
            int pos = atomicAdd(&hist[f], 1);
            pay[i] = p;
            meta[i] = ((unsigned)f << 16) | (unsigned)pos;
        }
    }
    __syncthreads();
    if (tid < 16) {
        int c = hist[tid];
        base[tid] = (c > 0) ? atomicAdd(&fill_f[cb * 16 + tid], c) : 0;
    }
    __syncthreads();
#pragma unroll
    for (int i = 0; i < 16; ++i) {
        if (meta[i] != 0xFFFFFFFFu) {
            int f = (int)(meta[i] >> 16);
            int pos = base[f] + (int)(meta[i] & 0xFFFFu);
            if (pos < CAP_F)
                edf[((unsigned)(cb * 16 + f)) * CAP_F + (unsigned)pos] = pay[i];
        }
    }
}

// ==================== pass B: in-place CSR compaction + degree/dinv (R6 form) =
// one block per fine bucket (64 nodes); scatter window 20 KB = L2-resident.
// ALSO converts its 64 owned rows of x to bf16 pre-scaled by dinv.

__global__ __launch_bounds__(256) void partB_kernel(const int* __restrict__ fill_f,
                                                    unsigned long long* __restrict__ edf,
                                                    float* __restrict__ dinv,
                                                    int* __restrict__ row_start,
                                                    int* __restrict__ row_cnt,
                                                    const float4* __restrict__ x4,
                                                    ushort4* __restrict__ xh4) {
    __shared__ int hist[64];
    __shared__ float degs[64];
    __shared__ int pref[64];
    const int tid = threadIdx.x;
    const int fb = blockIdx.x;
    const int node_base = fb * 64;
    const int cnt = min(fill_f[fb], CAP_F);
    if (tid < 64) { hist[tid] = 0; degs[tid] = 0.0f; }
    __syncthreads();

    unsigned long long pay[10];
    unsigned meta[10];
    int m = 0;
    for (int idx = tid; idx < cnt; idx += 256) {
        unsigned long long p = edf[(unsigned)fb * CAP_F + (unsigned)idx];
        int dl = (int)((p >> 17) & 63);
        int pos = atomicAdd(&hist[dl], 1);
        atomicAdd(&degs[dl], __uint_as_float((unsigned)(p >> 32)));
        pay[m] = p;
        meta[m] = ((unsigned)dl << 16) | (unsigned)pos;
        ++m;
    }
    __syncthreads();
    if (tid == 0) {
        int run = 0;
#pragma unroll
        for (int n = 0; n < 64; ++n) { pref[n] = run; run += hist[n]; }
    }
    __syncthreads();
    if (tid < 64) {
        int node = node_base + tid;
        if (node < N_NODES) {
            float dv = rsqrtf(degs[tid] + 1.0f);
            dinv[node] = dv;
            degs[tid] = dv;                 // republish dinv for the convert phase
            row_start[node] = fb * CAP_F + pref[tid];
            row_cnt[node] = hist[tid];
        }
    }
    // all reads completed before the barriers above -> safe in-place compaction
    for (int i = 0; i < m; ++i) {
        int dl = (int)(meta[i] >> 16);
        edf[(unsigned)fb * CAP_F + (unsigned)(pref[dl] + (int)(meta[i] & 0xFFFFu))] = pay[i];
    }
    __syncthreads();                        // degs[] now holds dinv for all 64 rows
    // fused xscale: xh[node,:] = bf16(x[node,:] * dinv[node]) for owned rows
#pragma unroll
    for (int i = 0; i < 8; ++i) {
        int idx = i * 256 + tid;            // [0,2048): 64 rows x 32 float4
        int r = idx >> 5;
        int node = node_base + r;
        if (node < N_NODES) {
            float dv = degs[r];
            float4 v = x4[(unsigned)node * 32u + (unsigned)(idx & 31)];
            ushort4 h;
            h.x = f2bf(v.x * dv); h.y = f2bf(v.y * dv);
            h.z = f2bf(v.z * dv); h.w = f2bf(v.w * dv);
            xh4[(unsigned)node * 32u + (unsigned)(idx & 31)] = h;
        }
    }
}

// ==================== fused gather + split-bf16 MFMA final =====================
// Block = 64 nodes (1568 blocks), 4 waves x 16 nodes each.
// Phase 1 (per wave, per node): R1 ping-pong gather pipeline (register
// accumulators, 8-deep prefetch) -> A = acc*di + x*di2 -> hi/lo bf16 ->
// XOR-swizzled LDS tile (4 KB/wave hi + 4 KB lo; 32 KB/block -> 5 blocks/CU;
// gather is MSHR-bound (R3), so 20 vs 25 waves/CU is throughput-neutral).
// Phase 2 (per wave): 16x128 @ 128x128 split-bf16 MFMA, A-frags from LDS,
// B-frags streamed from the 64 KB global wf tables (L2-resident).
// Deletes the 102 MB agg write+read round-trip and one kernel launch.

__global__ __launch_bounds__(256) void gatherf_kernel(const int* __restrict__ row_start,
                                                      const int* __restrict__ row_cnt,
                                                      const unsigned long long* __restrict__ edf,
                                                      const float* __restrict__ dinv,
                                                      const unsigned* __restrict__ xh,
                                                      const float2* __restrict__ x2,
                                                      const ushort* __restrict__ wf_hi,
                                                      const ushort* __restrict__ wf_lo,
                                                      const float* __restrict__ bias,
                                                      const float* __restrict__ x,
                                                      float* __restrict__ out) {
    __shared__ unsigned shA_hi[4][1024];    // per wave: 16 rows x 64 words (2 bf16/word)
    __shared__ unsigned shA_lo[4][1024];
    const int tid = threadIdx.x;
    const int wave = tid >> 6;
    const int lane = tid & 63;
    const int nb = blockIdx.x * 64 + wave * 16;     // wave's first node

    // ---------------- phase 1: gather 16 nodes, stage A hi/lo ----------------
    for (int i = 0; i < 16; ++i) {
        const int node = nb + i;
        const bool live = node < N_NODES;
        const int cnt = live ? row_cnt[node] : 0;
        const int start = live ? row_start[node] : 0;
        const float di = live ? dinv[node] : 0.0f;
        float ax0 = 0.f, ay0 = 0.f, ax1 = 0.f, ay1 = 0.f;

        for (int b = 0; b < cnt; b += 64) {
            int idx = b + lane;
            const bool valid = idx < cnt;
            if (!valid) idx = cnt - 1;                  // clamp: cached re-read
            unsigned long long p = edf[(unsigned)(start + idx)];
            int msrc = (int)(p & 0x1FFFFull);
            float mw = valid ? __uint_as_float((unsigned)(p >> 32)) : 0.0f;
            const int mcnt = min(64, cnt - b);
            const int ng = (mcnt + 7) >> 3;             // 8-edge groups (padded)

            unsigned va[8], vb[8];

#define PREF(buf, JB)                                                          \
            _Pragma("unroll")                                                  \
            for (int j = 0; j < 8; ++j) {                                      \
                int s = __builtin_amdgcn_readlane(msrc, (JB) + j);             \
                buf[j] = xh[(unsigned)s * 64u + (unsigned)lane];               \
            }
#define CONSUME(buf, JB)                                                       \
            _Pragma("unroll")                                                  \
            for (int j = 0; j < 8; ++j) {                                      \
                float w = __int_as_float(                                      \
                    __builtin_amdgcn_readlane(__float_as_int(mw), (JB) + j));  \
                if (j & 1) {                                                   \
                    ax1 = fmaf(__uint_as_float(buf[j] << 16), w, ax1);         \
                    ay1 = fmaf(__uint_as_float(buf[j] & 0xffff0000u), w, ay1); \
                } else {                                                       \
                    ax0 = fmaf(__uint_as_float(buf[j] << 16), w, ax0);         \
                    ay0 = fmaf(__uint_as_float(buf[j] & 0xffff0000u), w, ay0); \
                }                                                              \
            }

            PREF(va, 0);
            int g = 0;
            for (; g + 2 < ng; g += 2) {
                PREF(vb, (g + 1) * 8);      // issue next group while consuming va
                CONSUME(va, g * 8);
                PREF(va, (g + 2) * 8);      // ping-pong back
                CONSUME(vb, (g + 1) * 8);
            }
            if (g + 1 < ng) {               // two groups remain
                PREF(vb, (g + 1) * 8);
                CONSUME(va, g * 8);
                CONSUME(vb, (g + 1) * 8);
            } else {                        // one group remains
                CONSUME(va, g * 8);
            }
#undef PREF
#undef CONSUME
        }

        const float di2 = di * di;
        float2 xr = x2[(unsigned)(live ? node : 0) * 64u + lane];
        float a0 = (ax0 + ax1) * di + xr.x * di2;   // cols 2*lane, 2*lane+1
        float a1 = (ay0 + ay1) * di + xr.y * di2;
        unsigned h0 = f2bf(a0);
        unsigned l0 = f2bf(a0 - __uint_as_float(h0 << 16));
        unsigned h1 = f2bf(a1);
        unsigned l1 = f2bf(a1 - __uint_as_float(h1 << 16));
        // word = row*64 + lane, XOR-swizzled (word ^= (row&7)<<2): bank-uniform
        // for both the write (64 distinct words) and the b128 fragment reads.
        unsigned w = (unsigned)(i * 64 + lane) ^ ((unsigned)(i & 7) << 2);
        shA_hi[wave][w] = h0 | (h1 << 16);
        shA_lo[wave][w] = l0 | (l1 << 16);
    }
    __syncthreads();

    // ---------------- phase 2: 16x128 @ 128x128 split-bf16 MFMA --------------
    const int mrow = lane & 15;          // A row within tile / D column index
    const int kg = lane >> 4;
    s16x8 ah[4], al[4];
#pragma unroll
    for (int ks = 0; ks < 4; ++ks) {
        // row mrow, cols [ks*32+kg*8, +8) -> words mrow*64 + ks*16 + kg*4 .. +3
        unsigned w = (unsigned)(mrow * 64 + ks * 16 + kg * 4) ^ ((unsigned)(mrow & 7) << 2);
        ah[ks] = *(const s16x8*)&shA_hi[wave][w];
        al[ks] = *(const s16x8*)&shA_lo[wave][w];
    }

#pragma unroll
    for (int ct = 0; ct < 8; ++ct) {
        f32x4 acc = {0.f, 0.f, 0.f, 0.f};
#pragma unroll
        for (int ks = 0; ks < 4; ++ks) {
            const int fo = ((ct * 4 + ks) * 64 + lane) * 8;
            s16x8 bh = *(const s16x8*)&wf_hi[fo];   // L2-resident 64 KB tables
            s16x8 bl = *(const s16x8*)&wf_lo[fo];
            acc = __builtin_amdgcn_mfma_f32_16x16x32_bf16(ah[ks], bh, acc, 0, 0, 0);
            acc = __builtin_amdgcn_mfma_f32_16x16x32_bf16(ah[ks], bl, acc, 0, 0, 0);
            acc = __builtin_amdgcn_mfma_f32_16x16x32_bf16(al[ks], bh, acc, 0, 0, 0);
        }
        // C/D layout (m89-verified): col = lane&15, row = (lane>>4)*4 + reg
        const int col = ct * 16 + mrow;
        const float bv = bias[col];
#pragma unroll
        for (int v = 0; v < 4; ++v) {
            const int row = nb + kg * 4 + v;
            if (row < N_NODES) {
                float o = fmaxf(acc[v] + bv, 0.f) + x[(unsigned)row * 128u + col];
                out[(unsigned)row * 128u + col] = o;
            }
        }
    }
}

// ==================== fallback kernels (f32 bucket / CSR / scatter) ===========

__global__ __launch_bounds__(256) void bucket_f32_kernel(const int* __restrict__ ei,
                                                         const float* __restrict__ ew,
                                                         unsigned long long* __restrict__ packed,
                                                         int2* __restrict__ ed) {
    int e = blockIdx.x * 256 + threadIdx.x;
    int src = ei[e];
    int dst = ei[N_EDGES + e];
    float w = ew[e];
    unsigned long long inc = (1ull << 40) | (unsigned long long)(w * 4294967296.0f);
    unsigned long long old = atomicAdd(&packed[dst], inc);
    unsigned slot = (unsigned)(old >> 40);
    if (slot < CAP) {
        ed[(unsigned)dst * CAP + slot] = make_int2(src, __float_as_int(w));
    }
}

__global__ __launch_bounds__(256) void gatherb_f32_kernel(const unsigned long long* __restrict__ packed,
                                                          const int2* __restrict__ ed,
                                                          const float* __restrict__ dinv,
                                                          const float2* __restrict__ x2,
                                                          float2* __restrict__ agg2) {
    const int wave = threadIdx.x >> 6;
    const int lane = threadIdx.x & 63;
    const int node = blockIdx.x * 4 + wave;

    int cnt = (int)(packed[node] >> 40);
    cnt = min(cnt, CAP);
    const unsigned base = (unsigned)node * CAP;
    float2 acc = make_float2(0.f, 0.f);

    for (int b = 0; b < cnt; b += 64) {
        int idx = b + lane;
        if (idx >= cnt) idx = cnt - 1;
        int2 my = ed[base + idx];
        float wmy = __int_as_float(my.y) * dinv[my.x];
        int m = min(64, cnt - b);
#pragma unroll 8
        for (int j = 0; j < m; ++j) {
            int s = __builtin_amdgcn_readlane(my.x, j);
            float w = __int_as_float(__builtin_amdgcn_readlane(__float_as_int(wmy), j));
            float2 v = x2[(unsigned)s * 64u + lane];
            acc.x = fmaf(v.x, w, acc.x); acc.y = fmaf(v.y, w, acc.y);
        }
    }
    float di = dinv[node];
    acc.x *= di; acc.y *= di;
    agg2[(unsigned)node * 64u + lane] = acc;
}

__global__ __launch_bounds__(256) void count_deg_kernel(const int* __restrict__ ei,
                                                        const float* __restrict__ ew,
                                                        int* __restrict__ count,
                                                        float* __restrict__ deg) {
    int e = blockIdx.x * 256 + threadIdx.x;
    int dst = ei[N_EDGES + e];
    atomicAdd(&count[dst], 1);
    atomicAdd(&deg[dst], ew[e]);
}

__global__ __launch_bounds__(256) void scatter_kernel(const int* __restrict__ ei,
                                                      const float* __restrict__ ew,
                                                      const float* __restrict__ dinv,
                                                      const float4* __restrict__ x4,
                                                      float* __restrict__ agg) {
    unsigned gid = blockIdx.x * 256u + threadIdx.x;
    unsigned e  = gid >> 5;
    unsigned f4 = gid & 31u;
    int src = ei[e];
    int dst = ei[N_EDGES + e];
    float w = dinv[src] * ew[e] * dinv[dst];
    float4 v = x4[(unsigned)src * 32u + f4];
    float* o = agg + ((unsigned)dst * 128u + f4 * 4u);
    atomicAdd(o + 0, v.x * w);
    atomicAdd(o + 1, v.y * w);
    atomicAdd(o + 2, v.z * w);
    atomicAdd(o + 3, v.w * w);
}

// ============================ legacy vector final (fallback paths) ============

__global__ __launch_bounds__(256) void final_kernel(const float* __restrict__ agg_in,
                                                    const float* __restrict__ x,
                                                    const float* __restrict__ bias,
                                                    const float* __restrict__ dinv,
                                                    const float* __restrict__ Wt,
                                                    float* __restrict__ out) {
    __shared__ float sh_wt[16384];
    const int tid = threadIdx.x;
    {
        const float4* s4 = (const float4*)Wt;
        float4* d4 = (float4*)sh_wt;
#pragma unroll
        for (int i = 0; i < 16; ++i) d4[i * 256 + tid] = s4[i * 256 + tid];
    }
    __syncthreads();

    const int wave = tid >> 6;
    const int lane = tid & 63;
    const int rowbase = blockIdx.x * 32 + wave * 8;

    float areg[16];
#pragma unroll
    for (int r = 0; r < 8; ++r) {
        int row = rowbase + r;
        float di = dinv[row];
        float di2 = di * di;
        int base = row * 128;
        areg[2 * r]     = agg_in[base + lane]      + x[base + lane]      * di2;
        areg[2 * r + 1] = agg_in[base + 64 + lane] + x[base + 64 + lane] * di2;
    }

    float acc0[8], acc1[8];
#pragma unroll
    for (int r = 0; r < 8; ++r) { acc0[r] = 0.f; acc1[r] = 0.f; }

    const float2* wt2 = (const float2*)sh_wt;

#pragma unroll
    for (int kh = 0; kh < 2; ++kh) {
#pragma unroll 16
        for (int kk = 0; kk < 64; ++kk) {
            int k = kh * 64 + kk;
            float2 w = wt2[k * 64 + lane];
#pragma unroll
            for (int r = 0; r < 8; ++r) {
                float ak = __uint_as_float(
                    __builtin_amdgcn_readlane(__float_as_uint(areg[2 * r + kh]), kk));
                acc0[r] = fmaf(ak, w.x, acc0[r]);
                acc1[r] = fmaf(ak, w.y, acc1[r]);
            }
        }
    }

    float2 b = ((const float2*)bias)[lane];
#pragma unroll
    for (int r = 0; r < 8; ++r) {
        int row = rowbase + r;
        float2 xr = ((const float2*)x)[row * 64 + lane];
        float v0 = fmaxf(acc0[r] + b.x, 0.f) + xr.x;
        float v1 = fmaxf(acc1[r] + b.y, 0.f) + xr.y;
        ((float2*)out)[row * 64 + lane] = make_float2(v0, v1);
    }
}

// ===============================================================================

extern "C" void kernel_launch(void* const* d_in, const int* in_sizes, int n_in,
                              void* d_out, int out_size, void* d_ws, size_t ws_size,
                              hipStream_t stream) {
    const float* x    = (const float*)d_in[0];
    const float* W    = (const float*)d_in[1];
    const float* bias = (const float*)d_in[2];
    const float* ew   = (const float*)d_in[3];
    const int*   ei   = (const int*)d_in[4];
    float* out = (float*)d_out;
    char* ws = (char*)d_ws;

    // ---------- primary layout (hierarchical partition) ----------
    // xh bf16[N*128]       [0, 25600000)
    // Wfrag hi/lo ushort   [25600000, 25665536)
    // dinv f32[N]          [25665536, 26065536)
    // row_start int[N]     [26065536, 26465536)
    // row_cnt int[N]       [26465536, 26865536)
    // fill_c int[98]       [26865536, ...) contiguous with fill_f int[1568]
    // edc u64[98*36864]    [26872256, 55773632)
    // edf u64[1568*2560]   [55773632, 87886272)
    unsigned short* xhA  = (unsigned short*)ws;
    ushort* wfhi     = (ushort*)(ws + 25600000);
    ushort* wflo     = wfhi + 16384;
    float* dinvA     = (float*)(ws + 25665536);
    int*   row_start = (int*)  (ws + 26065536);
    int*   row_cnt   = (int*)  (ws + 26465536);
    int*   fill_c    = (int*)  (ws + 26865536);
    int*   fill_f    = fill_c + NB_C;
    unsigned long long* edc = (unsigned long long*)(ws + 26872256);
    unsigned long long* edf = (unsigned long long*)(ws + 55773632);
    const size_t WS_PART = 87886272ull;

    // ---------- fallback layout (round-3 bucket) ----------
    unsigned long long* packed = (unsigned long long*)ws;
    float* dinvB = (float*)(ws + 800000);
    float* WtB   = (float*)(ws + 1200000);
    int2*  edB   = (int2*)(ws + 1265536);
    const size_t WS_BUCKET = 1265536ull + (size_t)N_NODES * CAP * 8ull;   // ~78.1 MB

    if (ws_size >= WS_PART) {
        prep_kernel<<<71, 256, 0, stream>>>(W, wfhi, wflo, fill_c);
        partA1_kernel<<<(N_EDGES + 4095) / 4096, 256, 0, stream>>>(ei, ew, fill_c, edc);
        partA2_kernel<<<NB_C * 9, 256, 0, stream>>>(fill_c, edc, fill_f, edf);
        partB_kernel<<<NB_F, 256, 0, stream>>>(fill_f, edf, dinvA, row_start, row_cnt,
                                               (const float4*)x, (ushort4*)xhA);
        gatherf_kernel<<<NB_F, 256, 0, stream>>>(row_start, row_cnt, edf, dinvA,
                                                 (const unsigned*)xhA, (const float2*)x,
                                                 wfhi, wflo, bias, x, out);
    } else if (ws_size >= WS_BUCKET) {
        float* WtB_f = WtB;
        zero_u64_kernel<<<(N_NODES + 255) / 256, 256, 0, stream>>>(packed, N_NODES);
        wt_kernel<<<64, 256, 0, stream>>>(W, WtB_f);
        bucket_f32_kernel<<<N_EDGES / 256, 256, 0, stream>>>(ei, ew, packed, edB);
        dinv_packed_kernel<<<(N_NODES + 255) / 256, 256, 0, stream>>>(packed, dinvB);
        gatherb_f32_kernel<<<N_NODES / 4, 256, 0, stream>>>(packed, edB, dinvB,
                                                            (const float2*)x, (float2*)out);
        final_kernel<<<N_NODES / 32, 256, 0, stream>>>(out, x, bias, dinvB, WtB_f, out);
    } else {
        float* deg   = (float*)(ws);
        float* Wt    = (float*)(ws + 400000);
        int*   count = (int*)  (ws + 465536);
        zero_f_kernel<<<(N_NODES + 255) / 256, 256, 0, stream>>>(deg, N_NODES);
        zero_i_kernel<<<(N_NODES + 255) / 256, 256, 0, stream>>>(count, N_NODES);
        wt_kernel<<<64, 256, 0, stream>>>(W, Wt);
        zero_f4_kernel<<<(N_NODES * DIM / 4) / 256, 256, 0, stream>>>((float4*)out,
                                                                      N_NODES * DIM / 4);
        count_deg_kernel<<<N_EDGES / 256, 256, 0, stream>>>(ei, ew, count, deg);
        dinv_kernel<<<(N_NODES + 255) / 256, 256, 0, stream>>>(deg);
        scatter_kernel<<<(N_EDGES / 256) * 32, 256, 0, stream>>>(ei, ew, deg,
                                                                 (const float4*)x, out);
        final_kernel<<<N_NODES / 32, 256, 0, stream>>>(out, x, bias, deg, Wt, out);
    }
}

// Round 9
// 351.663 us; speedup vs baseline: 1.0900x; 1.0528x over previous
//
#include <hip/hip_runtime.h>

#define N_NODES 100000
#define N_EDGES 3200000
#define DIM 128

// hierarchical partition geometry
#define NB_C  98       // coarse buckets: dst>>10 (1024 nodes each)
#define CAP_C 36864    // avg 32653, sigma~181 -> +23 sigma
#define NB_F  1568     // fine buckets: 64 nodes each (NB_C*16)
#define CAP_F 2560     // avg 2041, sigma~45 -> +11 sigma
#define CAP   96       // legacy fallback bucket capacity

// payload u64: w_bits[63:32] | dst&1023 [26:17] | src [16:0]

typedef __attribute__((ext_vector_type(4))) float f32x4;
typedef __attribute__((ext_vector_type(8))) short s16x8;

// ============================ helpers ============================

__device__ __forceinline__ unsigned short f2bf(float f) {   // round-to-nearest-even
    unsigned u = __float_as_uint(f);
    return (unsigned short)((u + 0x7fffu + ((u >> 16) & 1u)) >> 16);
}

// ============================ small utility kernels ============================

__global__ __launch_bounds__(256) void zero_i_kernel(int* __restrict__ p, int n) {
    int i = blockIdx.x * 256 + threadIdx.x;
    if (i < n) p[i] = 0;
}

__global__ __launch_bounds__(256) void zero_f_kernel(float* __restrict__ p, int n) {
    int i = blockIdx.x * 256 + threadIdx.x;
    if (i < n) p[i] = 0.0f;
}

__global__ __launch_bounds__(256) void zero_u64_kernel(unsigned long long* __restrict__ p, int n) {
    int i = blockIdx.x * 256 + threadIdx.x;
    if (i < n) p[i] = 0ull;
}

__global__ __launch_bounds__(256) void zero_f4_kernel(float4* __restrict__ p, int n4) {
    int i = blockIdx.x * 256 + threadIdx.x;
    if (i < n4) p[i] = make_float4(0.f, 0.f, 0.f, 0.f);
}

__global__ __launch_bounds__(256) void dinv_kernel(float* __restrict__ deg) {
    int i = blockIdx.x * 256 + threadIdx.x;
    if (i < N_NODES) deg[i] = rsqrtf(deg[i] + 1.0f);
}

__global__ __launch_bounds__(256) void dinv_packed_kernel(const unsigned long long* __restrict__ packed,
                                                          float* __restrict__ dinv) {
    int i = blockIdx.x * 256 + threadIdx.x;
    if (i < N_NODES) {
        unsigned long long p = packed[i];
        float deg = (float)(p & 0xFFFFFFFFFFull) * (1.0f / 4294967296.0f);
        dinv[i] = rsqrtf(deg + 1.0f);
    }
}

__global__ __launch_bounds__(256) void wt_kernel(const float* __restrict__ W,
                                                 float* __restrict__ Wt) {
    int idx = blockIdx.x * 256 + threadIdx.x;
    int j = idx >> 7, k = idx & 127;
    Wt[k * 128 + j] = W[idx];
}

// ==================== prep: W -> MFMA B-fragment tables (hi/lo bf16) + fills ==
// Split precision: W = Wh + Wl with Wh = bf16(W), Wl = bf16(W - Wh).
// Fragment order for mfma_f32_16x16x32_bf16 B-operand:
//   idx = ((ct*4+ks)*64 + lane)*8 + j ; col = ct*16+(lane&15),
//   k = ks*32+(lane>>4)*8+j ; value = W[col][k]  (B[k][n] = W^T[k][n] = W[n][k])
// grid: [0,64) fragment build (16384 elems); [64,71) zero 1666 fill ints

__global__ __launch_bounds__(256) void prep_kernel(const float* __restrict__ W,
                                                   ushort* __restrict__ wf_hi,
                                                   ushort* __restrict__ wf_lo,
                                                   int* __restrict__ fills) {
    const int b = blockIdx.x;
    const int tid = threadIdx.x;
    if (b < 64) {
        int idx  = b * 256 + tid;           // [0,16384)
        int j    = idx & 7;
        int lane = (idx >> 3) & 63;
        int ks   = (idx >> 9) & 3;
        int ct   = idx >> 11;
        int col  = ct * 16 + (lane & 15);
        int k    = ks * 32 + ((lane >> 4) << 3) + j;
        float w  = W[col * 128 + k];
        unsigned short hb = f2bf(w);
        float rem = w - __uint_as_float((unsigned)hb << 16);
        wf_hi[idx] = hb;
        wf_lo[idx] = f2bf(rem);
    } else {
        int i = (b - 64) * 256 + tid;
        if (i < NB_C + NB_F) fills[i] = 0;
    }
}

// ==================== pass A1: edges -> 98 coarse buckets (R6 form) ==========

__global__ __launch_bounds__(256) void partA1_kernel(const int* __restrict__ ei,
                                                     const float* __restrict__ ew,
                                                     int* __restrict__ fill_c,
                                                     unsigned long long* __restrict__ edc) {
    __shared__ int hist[NB_C];
    __shared__ int base[NB_C];
    const int tid = threadIdx.x;
    const int blockbase = blockIdx.x * 4096;
    for (int i = tid; i < NB_C; i += 256) hist[i] = 0;
    __syncthreads();

    unsigned long long pay[16];
    unsigned meta[16];
#pragma unroll
    for (int i = 0; i < 16; ++i) {
        int e = blockbase + i * 256 + tid;
        meta[i] = 0xFFFFFFFFu;
        if (e < N_EDGES) {
            int src = ei[e];
            int dst = ei[N_EDGES + e];
            float w = ew[e];
            int cb = dst >> 10;
            int pos = atomicAdd(&hist[cb], 1);
            pay[i] = ((unsigned long long)__float_as_uint(w) << 32)
                   | ((unsigned)(dst & 1023) << 17) | (unsigned)src;
            meta[i] = ((unsigned)cb << 16) | (unsigned)pos;
        }
    }
    __syncthreads();
    for (int c = tid; c < NB_C; c += 256) {
        int cnt = hist[c];
        base[c] = (cnt > 0) ? atomicAdd(&fill_c[c], cnt) : 0;
    }
    __syncthreads();
#pragma unroll
    for (int i = 0; i < 16; ++i) {
        if (meta[i] != 0xFFFFFFFFu) {
            int cb = (int)(meta[i] >> 16);
            int pos = base[cb] + (int)(meta[i] & 0xFFFFu);
            if (pos < CAP_C)
                edc[(unsigned)cb * CAP_C + (unsigned)pos] = pay[i];
        }
    }
}

// ==================== pass A2: coarse -> 16 fine sub-buckets each (R6 form) ===
// 9 slice-blocks per coarse bucket (9*4096 >= CAP_C)

__global__ __launch_bounds__(256) void partA2_kernel(const int* __restrict__ fill_c,
                                                     const unsigned long long* __restrict__ edc,
                                                     int* __restrict__ fill_f,
                                                     unsigned long long* __restrict__ edf) {
    __shared__ int hist[16];
    __shared__ int base[16];
    const int tid = threadIdx.x;
    const int cb = blockIdx.x / 9;
    const int lo = (blockIdx.x % 9) * 4096;
    const int cnt_c = min(fill_c[cb], CAP_C);
    const int hi = min(lo + 4096, cnt_c);
    if (tid < 16) hist[tid] = 0;
    __syncthreads();

    unsigned long long pay[16];
    unsigned meta[16];
#pragma unroll
    for (int i = 0; i < 16; ++i) {
        int idx = lo + i * 256 + tid;
        meta[i] = 0xFFFFFFFFu;
        if (idx < hi) {
            unsigned long long p = edc[(unsigned)cb * CAP_C + (unsigned)idx];
            int f = (int)((p >> 23) & 15);      // dst bits [6,10)
            int pos = atomicAdd(&hist[f], 1);
            pay[i] = p;
            meta[i] = ((unsigned)f << 16) | (unsigned)pos;
        }
    }
    __syncthreads();
    if (tid < 16) {
        int c = hist[tid];
        base[tid] = (c > 0) ? atomicAdd(&fill_f[cb * 16 + tid], c) : 0;
    }
    __syncthreads();
#pragma unroll
    for (int i = 0; i < 16; ++i) {
        if (meta[i] != 0xFFFFFFFFu) {
            int f = (int)(meta[i] >> 16);
            int pos = base[f] + (int)(meta[i] & 0xFFFFu);
            if (pos < CAP_F)
                edf[((unsigned)(cb * 16 + f)) * CAP_F + (unsigned)pos] = pay[i];
        }
    }
}

// ==================== pass B: in-place CSR compaction + degree/dinv ===========
// one block per fine bucket (64 nodes); scatter window 20 KB = L2-resident.
// THIS ROUND (isolated change): (1) STATIC-indexed pay/meta (rule #20 — the
// R6 dynamically-indexed pay[m] spills ~120B/thread to scratch); (2) ONE u64
// LDS atomic per edge (count | deg_fx24<<32) instead of int+float — halves
// the serialized same-bin atomic chain. Deg fixed-point 2^24: max run-sum
// ~150 -> no overflow; abs err ~1e-5 (<< bf16 noise).
// ALSO converts its 64 owned rows of x to bf16 pre-scaled by dinv (R6 form).

__global__ __launch_bounds__(256) void partB_kernel(const int* __restrict__ fill_f,
                                                    unsigned long long* __restrict__ edf,
                                                    float* __restrict__ dinv,
                                                    int* __restrict__ row_start,
                                                    int* __restrict__ row_cnt,
                                                    const float4* __restrict__ x4,
                                                    ushort4* __restrict__ xh4) {
    __shared__ unsigned long long hd[64];   // low32 = count, high32 = deg fx2^24
    __shared__ int pref[64];
    __shared__ float dinv_s[64];
    const int tid = threadIdx.x;
    const int fb = blockIdx.x;
    const int node_base = fb * 64;
    const int cnt = min(fill_f[fb], CAP_F);
    if (tid < 64) hd[tid] = 0ull;
    __syncthreads();

    unsigned long long pay[10];
    unsigned meta[10];
#pragma unroll
    for (int it = 0; it < 10; ++it) {       // CAP_F/256 = 10, static indices
        int idx = it * 256 + tid;
        meta[it] = 0xFFFFFFFFu;
        if (idx < cnt) {
            unsigned long long p = edf[(unsigned)fb * CAP_F + (unsigned)idx];
            int dl = (int)((p >> 17) & 63);
            float w = __uint_as_float((unsigned)(p >> 32));
            unsigned long long inc = 1ull |
                ((unsigned long long)(unsigned)(w * 16777216.0f + 0.5f) << 32);
            unsigned long long old = atomicAdd(&hd[dl], inc);
            pay[it] = p;
            meta[it] = ((unsigned)dl << 16) | (unsigned)(old & 0xFFFFull);
        }
    }
    __syncthreads();
    if (tid == 0) {
        int run = 0;
#pragma unroll
        for (int n = 0; n < 64; ++n) { pref[n] = run; run += (int)(hd[n] & 0xFFFFFFFFull); }
    }
    __syncthreads();
    if (tid < 64) {
        int node = node_base + tid;
        if (node < N_NODES) {
            float deg = (float)(unsigned)(hd[tid] >> 32) * (1.0f / 16777216.0f);
            float dv = rsqrtf(deg + 1.0f);
            dinv[node] = dv;
            dinv_s[tid] = dv;
            row_start[node] = fb * CAP_F + pref[tid];
            row_cnt[node] = (int)(hd[tid] & 0xFFFFFFFFull);
        }
    }
    // all reads completed before the barriers above -> safe in-place compaction
#pragma unroll
    for (int it = 0; it < 10; ++it) {
        if (meta[it] != 0xFFFFFFFFu) {
            int dl = (int)(meta[it] >> 16);
            edf[(unsigned)fb * CAP_F + (unsigned)(pref[dl] + (int)(meta[it] & 0xFFFFu))] = pay[it];
        }
    }
    __syncthreads();                        // dinv_s[] valid for all 64 rows
    // fused xscale: xh[node,:] = bf16(x[node,:] * dinv[node]) for owned rows
#pragma unroll
    for (int i = 0; i < 8; ++i) {
        int idx = i * 256 + tid;            // [0,2048): 64 rows x 32 float4
        int r = idx >> 5;
        int node = node_base + r;
        if (node < N_NODES) {
            float dv = dinv_s[r];
            float4 v = x4[(unsigned)node * 32u + (unsigned)(idx & 31)];
            ushort4 h;
            h.x = f2bf(v.x * dv); h.y = f2bf(v.y * dv);
            h.z = f2bf(v.z * dv); h.w = f2bf(v.w * dv);
            xh4[(unsigned)node * 32u + (unsigned)(idx & 31)] = h;
        }
    }
}

// ==================== gather over exact CSR runs, bf16 x (pre-scaled) ========
// R1 version, byte-for-byte (107 us verified): node-per-wave, register
// accumulators, 8-deep ping-pong prefetch pipeline. MSHR*latency-bound plateau.

__global__ __launch_bounds__(256) void gatherc_kernel(const int* __restrict__ row_start,
                                                      const int* __restrict__ row_cnt,
                                                      const unsigned long long* __restrict__ edf,
                                                      const float* __restrict__ dinv,
                                                      const unsigned* __restrict__ xh,
                                                      float2* __restrict__ agg2) {
    const int lane = threadIdx.x & 63;
    const int node = blockIdx.x * 4 + (threadIdx.x >> 6);

    const int cnt = row_cnt[node];
    const int start = row_start[node];
    float ax0 = 0.f, ay0 = 0.f, ax1 = 0.f, ay1 = 0.f;   // 4 independent FMA chains

    for (int b = 0; b < cnt; b += 64) {
        int idx = b + lane;
        const bool valid = idx < cnt;
        if (!valid) idx = cnt - 1;                      // clamp: cached re-read
        unsigned long long p = edf[(unsigned)(start + idx)];
        int msrc = (int)(p & 0x1FFFFull);
        float mw = valid ? __uint_as_float((unsigned)(p >> 32)) : 0.0f;  // zero-pad
        const int mcnt = min(64, cnt - b);
        const int ng = (mcnt + 7) >> 3;                 // 8-edge groups (padded)

        unsigned va[8], vb[8];

#define PREF(buf, JB)                                                          \
        _Pragma("unroll")                                                      \
        for (int j = 0; j < 8; ++j) {                                          \
            int s = __builtin_amdgcn_readlane(msrc, (JB) + j);                 \
            buf[j] = xh[(unsigned)s * 64u + (unsigned)lane];                   \
        }
#define CONSUME(buf, JB)                                                       \
        _Pragma("unroll")                                                      \
        for (int j = 0; j < 8; ++j) {                                          \
            float w = __int_as_float(                                          \
                __builtin_amdgcn_readlane(__float_as_int(mw), (JB) + j));      \
            if (j & 1) {                                                       \
                ax1 = fmaf(__uint_as_float(buf[j] << 16), w, ax1);             \
                ay1 = fmaf(__uint_as_float(buf[j] & 0xffff0000u), w, ay1);     \
            } else {                                                           \
                ax0 = fmaf(__uint_as_float(buf[j] << 16), w, ax0);             \
                ay0 = fmaf(__uint_as_float(buf[j] & 0xffff0000u), w, ay0);     \
            }                                                                  \
        }

        PREF(va, 0);
        int g = 0;
        for (; g + 2 < ng; g += 2) {
            PREF(vb, (g + 1) * 8);      // issue next group while consuming va
            CONSUME(va, g * 8);
            PREF(va, (g + 2) * 8);      // ping-pong back
            CONSUME(vb, (g + 1) * 8);
        }
        if (g + 1 < ng) {               // two groups remain
            PREF(vb, (g + 1) * 8);
            CONSUME(va, g * 8);
            CONSUME(vb, (g + 1) * 8);
        } else {                        // one group remains
            CONSUME(va, g * 8);
        }
#undef PREF
#undef CONSUME
    }

    float di = dinv[node];
    agg2[(unsigned)node * 64u + lane] = make_float2((ax0 + ax1) * di, (ay0 + ay1) * di);
}

// ==================== fallback kernels (f32 bucket / CSR / scatter) ===========

__global__ __launch_bounds__(256) void bucket_f32_kernel(const int* __restrict__ ei,
                                                         const float* __restrict__ ew,
                                                         unsigned long long* __restrict__ packed,
                                                         int2* __restrict__ ed) {
    int e = blockIdx.x * 256 + threadIdx.x;
    int src = ei[e];
    int dst = ei[N_EDGES + e];
    float w = ew[e];
    unsigned long long inc = (1ull << 40) | (unsigned long long)(w * 4294967296.0f);
    unsigned long long old = atomicAdd(&packed[dst], inc);
    unsigned slot = (unsigned)(old >> 40);
    if (slot < CAP) {
        ed[(unsigned)dst * CAP + slot] = make_int2(src, __float_as_int(w));
    }
}

__global__ __launch_bounds__(256) void gatherb_f32_kernel(const unsigned long long* __restrict__ packed,
                                                          const int2* __restrict__ ed,
                                                          const float* __restrict__ dinv,
                                                          const float2* __restrict__ x2,
                                                          float2* __restrict__ agg2) {
    const int wave = threadIdx.x >> 6;
    const int lane = threadIdx.x & 63;
    const int node = blockIdx.x * 4 + wave;

    int cnt = (int)(packed[node] >> 40);
    cnt = min(cnt, CAP);
    const unsigned base = (unsigned)node * CAP;
    float2 acc = make_float2(0.f, 0.f);

    for (int b = 0; b < cnt; b += 64) {
        int idx = b + lane;
        if (idx >= cnt) idx = cnt - 1;
        int2 my = ed[base + idx];
        float wmy = __int_as_float(my.y) * dinv[my.x];
        int m = min(64, cnt - b);
#pragma unroll 8
        for (int j = 0; j < m; ++j) {
            int s = __builtin_amdgcn_readlane(my.x, j);
            float w = __int_as_float(__builtin_amdgcn_readlane(__float_as_int(wmy), j));
            float2 v = x2[(unsigned)s * 64u + lane];
            acc.x = fmaf(v.x, w, acc.x); acc.y = fmaf(v.y, w, acc.y);
        }
    }
    float di = dinv[node];
    acc.x *= di; acc.y *= di;
    agg2[(unsigned)node * 64u + lane] = acc;
}

__global__ __launch_bounds__(256) void count_deg_kernel(const int* __restrict__ ei,
                                                        const float* __restrict__ ew,
                                                        int* __restrict__ count,
                                                        float* __restrict__ deg) {
    int e = blockIdx.x * 256 + threadIdx.x;
    int dst = ei[N_EDGES + e];
    atomicAdd(&count[dst], 1);
    atomicAdd(&deg[dst], ew[e]);
}

__global__ __launch_bounds__(256) void scatter_kernel(const int* __restrict__ ei,
                                                      const float* __restrict__ ew,
                                                      const float* __restrict__ dinv,
                                                      const float4* __restrict__ x4,
                                                      float* __restrict__ agg) {
    unsigned gid = blockIdx.x * 256u + threadIdx.x;
    unsigned e  = gid >> 5;
    unsigned f4 = gid & 31u;
    int src = ei[e];
    int dst = ei[N_EDGES + e];
    float w = dinv[src] * ew[e] * dinv[dst];
    float4 v = x4[(unsigned)src * 32u + f4];
    float* o = agg + ((unsigned)dst * 128u + f4 * 4u);
    atomicAdd(o + 0, v.x * w);
    atomicAdd(o + 1, v.y * w);
    atomicAdd(o + 2, v.z * w);
    atomicAdd(o + 3, v.w * w);
}

// ============================ final: split-bf16 MFMA GEMM + epilogue ==========
// out[i,:] = relu( (agg[i,:] + x[i,:]*dinv[i]^2) @ W^T + bias ) + x[i,:]
// A = Ah+Al, W = Wh+Wl (bf16 splits); A@W ~= Ah@Wh + Ah@Wl + Al@Wh
// (error ~2^-17 rel, keeps f32-grade absmax). UNCHANGED (R6 form).

__global__ __launch_bounds__(256) void final_mfma_kernel(const float* __restrict__ agg_in,
                                                         const float* __restrict__ x,
                                                         const float* __restrict__ bias,
                                                         const float* __restrict__ dinv,
                                                         const ushort* __restrict__ wf_hi,
                                                         const ushort* __restrict__ wf_lo,
                                                         float* __restrict__ out) {
    __shared__ ushort sh_hi[16384];
    __shared__ ushort sh_lo[16384];
    const int tid = threadIdx.x;
    {
        const float4* sh4 = (const float4*)wf_hi;
        const float4* sl4 = (const float4*)wf_lo;
        float4* dh = (float4*)sh_hi;
        float4* dl = (float4*)sh_lo;
#pragma unroll
        for (int i = 0; i < 8; ++i) {
            dh[i * 256 + tid] = sh4[i * 256 + tid];
            dl[i * 256 + tid] = sl4[i * 256 + tid];
        }
    }
    __syncthreads();

    const int wave = tid >> 6;
    const int lane = tid & 63;
    const int r0 = blockIdx.x * 64 + wave * 16;
    const int mrow = lane & 15;          // A row within tile
    const int kg = lane >> 4;            // k-group
    const int arow = min(r0 + mrow, N_NODES - 1);   // clamped (tail block)
    const float di = dinv[arow];
    const float di2 = di * di;

    // A-fragments: lane holds 8 k-contiguous elems at k = ks*32 + kg*8 + j
    s16x8 ah[4], al[4];
#pragma unroll
    for (int ks = 0; ks < 4; ++ks) {
        const float* ap = agg_in + (unsigned)arow * 128u + ks * 32 + kg * 8;
        const float* xp = x      + (unsigned)arow * 128u + ks * 32 + kg * 8;
        float4 a0 = *(const float4*)ap;
        float4 a1 = *(const float4*)(ap + 4);
        float4 x0 = *(const float4*)xp;
        float4 x1 = *(const float4*)(xp + 4);
        float v[8] = {a0.x + x0.x * di2, a0.y + x0.y * di2,
                      a0.z + x0.z * di2, a0.w + x0.w * di2,
                      a1.x + x1.x * di2, a1.y + x1.y * di2,
                      a1.z + x1.z * di2, a1.w + x1.w * di2};
        s16x8 h, l;
#pragma unroll
        for (int j = 0; j < 8; ++j) {
            unsigned short hb = f2bf(v[j]);
            h[j] = (short)hb;
            l[j] = (short)f2bf(v[j] - __uint_as_float((unsigned)hb << 16));
        }
        ah[ks] = h; al[ks] = l;
    }

#pragma unroll
    for (int ct = 0; ct < 8; ++ct) {
        f32x4 acc = {0.f, 0.f, 0.f, 0.f};
#pragma unroll
        for (int ks = 0; ks < 4; ++ks) {
            const int fo = ((ct * 4 + ks) * 64 + lane) * 8;
            s16x8 bh = *(const s16x8*)&sh_hi[fo];
            s16x8 bl = *(const s16x8*)&sh_lo[fo];
            acc = __builtin_amdgcn_mfma_f32_16x16x32_bf16(ah[ks], bh, acc, 0, 0, 0);
            acc = __builtin_amdgcn_mfma_f32_16x16x32_bf16(ah[ks], bl, acc, 0, 0, 0);
            acc = __builtin_amdgcn_mfma_f32_16x16x32_bf16(al[ks], bh, acc, 0, 0, 0);
        }
        // C/D layout (m89-verified): col = lane&15, row = (lane>>4)*4 + reg
        const int col = ct * 16 + mrow;
        const float bv = bias[col];
#pragma unroll
        for (int v = 0; v < 4; ++v) {
            const int row = r0 + kg * 4 + v;
            if (row < N_NODES) {
                float o = fmaxf(acc[v] + bv, 0.f) + x[(unsigned)row * 128u + col];
                out[(unsigned)row * 128u + col] = o;
            }
        }
    }
}

// ============================ legacy vector final (fallback paths) ============

__global__ __launch_bounds__(256) void final_kernel(const float* __restrict__ agg_in,
                                                    const float* __restrict__ x,
                                                    const float* __restrict__ bias,
                                                    const float* __restrict__ dinv,
                                                    const float* __restrict__ Wt,
                                                    float* __restrict__ out) {
    __shared__ float sh_wt[16384];
    const int tid = threadIdx.x;
    {
        const float4* s4 = (const float4*)Wt;
        float4* d4 = (float4*)sh_wt;
#pragma unroll
        for (int i = 0; i < 16; ++i) d4[i * 256 + tid] = s4[i * 256 + tid];
    }
    __syncthreads();

    const int wave = tid >> 6;
    const int lane = tid & 63;
    const int rowbase = blockIdx.x * 32 + wave * 8;

    float areg[16];
#pragma unroll
    for (int r = 0; r < 8; ++r) {
        int row = rowbase + r;
        float di = dinv[row];
        float di2 = di * di;
        int base = row * 128;
        areg[2 * r]     = agg_in[base + lane]      + x[base + lane]      * di2;
        areg[2 * r + 1] = agg_in[base + 64 + lane] + x[base + 64 + lane] * di2;
    }

    float acc0[8], acc1[8];
#pragma unroll
    for (int r = 0; r < 8; ++r) { acc0[r] = 0.f; acc1[r] = 0.f; }

    const float2* wt2 = (const float2*)sh_wt;

#pragma unroll
    for (int kh = 0; kh < 2; ++kh) {
#pragma unroll 16
        for (int kk = 0; kk < 64; ++kk) {
            int k = kh * 64 + kk;
            float2 w = wt2[k * 64 + lane];
#pragma unroll
            for (int r = 0; r < 8; ++r) {
                float ak = __uint_as_float(
                    __builtin_amdgcn_readlane(__float_as_uint(areg[2 * r + kh]), kk));
                acc0[r] = fmaf(ak, w.x, acc0[r]);
                acc1[r] = fmaf(ak, w.y, acc1[r]);
            }
        }
    }

    float2 b = ((const float2*)bias)[lane];
#pragma unroll
    for (int r = 0; r < 8; ++r) {
        int row = rowbase + r;
        float2 xr = ((const float2*)x)[row * 64 + lane];
        float v0 = fmaxf(acc0[r] + b.x, 0.f) + xr.x;
        float v1 = fmaxf(acc1[r] + b.y, 0.f) + xr.y;
        ((float2*)out)[row * 64 + lane] = make_float2(v0, v1);
    }
}

// ===============================================================================

extern "C" void kernel_launch(void* const* d_in, const int* in_sizes, int n_in,
                              void* d_out, int out_size, void* d_ws, size_t ws_size,
                              hipStream_t stream) {
    const float* x    = (const float*)d_in[0];
    const float* W    = (const float*)d_in[1];
    const float* bias = (const float*)d_in[2];
    const float* ew   = (const float*)d_in[3];
    const int*   ei   = (const int*)d_in[4];
    float* out = (float*)d_out;
    char* ws = (char*)d_ws;

    // ---------- primary layout (hierarchical partition) ----------
    // xh bf16[N*128]       [0, 25600000)
    // Wfrag hi/lo ushort   [25600000, 25665536)
    // dinv f32[N]          [25665536, 26065536)
    // row_start int[N]     [26065536, 26465536)
    // row_cnt int[N]       [26465536, 26865536)
    // fill_c int[98]       [26865536, ...) contiguous with fill_f int[1568]
    // edc u64[98*36864]    [26872256, 55773632)
    // edf u64[1568*2560]   [55773632, 87886272)
    unsigned short* xhA  = (unsigned short*)ws;
    ushort* wfhi     = (ushort*)(ws + 25600000);
    ushort* wflo     = wfhi + 16384;
    float* dinvA     = (float*)(ws + 25665536);
    int*   row_start = (int*)  (ws + 26065536);
    int*   row_cnt   = (int*)  (ws + 26465536);
    int*   fill_c    = (int*)  (ws + 26865536);
    int*   fill_f    = fill_c + NB_C;
    unsigned long long* edc = (unsigned long long*)(ws + 26872256);
    unsigned long long* edf = (unsigned long long*)(ws + 55773632);
    const size_t WS_PART = 87886272ull;

    // ---------- fallback layout (round-3 bucket) ----------
    unsigned long long* packed = (unsigned long long*)ws;
    float* dinvB = (float*)(ws + 800000);
    float* WtB   = (float*)(ws + 1200000);
    int2*  edB   = (int2*)(ws + 1265536);
    const size_t WS_BUCKET = 1265536ull + (size_t)N_NODES * CAP * 8ull;   // ~78.1 MB

    if (ws_size >= WS_PART) {
        prep_kernel<<<71, 256, 0, stream>>>(W, wfhi, wflo, fill_c);
        partA1_kernel<<<(N_EDGES + 4095) / 4096, 256, 0, stream>>>(ei, ew, fill_c, edc);
        partA2_kernel<<<NB_C * 9, 256, 0, stream>>>(fill_c, edc, fill_f, edf);
        partB_kernel<<<NB_F, 256, 0, stream>>>(fill_f, edf, dinvA, row_start, row_cnt,
                                               (const float4*)x, (ushort4*)xhA);
        gatherc_kernel<<<N_NODES / 4, 256, 0, stream>>>(row_start, row_cnt, edf, dinvA,
                                                        (const unsigned*)xhA, (float2*)out);
        final_mfma_kernel<<<(N_NODES + 63) / 64, 256, 0, stream>>>(out, x, bias, dinvA,
                                                                   wfhi, wflo, out);
    } else if (ws_size >= WS_BUCKET) {
        zero_u64_kernel<<<(N_NODES + 255) / 256, 256, 0, stream>>>(packed, N_NODES);
        wt_kernel<<<64, 256, 0, stream>>>(W, WtB);
        bucket_f32_kernel<<<N_EDGES / 256, 256, 0, stream>>>(ei, ew, packed, edB);
        dinv_packed_kernel<<<(N_NODES + 255) / 256, 256, 0, stream>>>(packed, dinvB);
        gatherb_f32_kernel<<<N_NODES / 4, 256, 0, stream>>>(packed, edB, dinvB,
                                                            (const float2*)x, (float2*)out);
        final_kernel<<<N_NODES / 32, 256, 0, stream>>>(out, x, bias, dinvB, WtB, out);
    } else {
        float* deg   = (float*)(ws);
        float* Wt    = (float*)(ws + 400000);
        int*   count = (int*)  (ws + 465536);
        zero_f_kernel<<<(N_NODES + 255) / 256, 256, 0, stream>>>(deg, N_NODES);
        zero_i_kernel<<<(N_NODES + 255) / 256, 256, 0, stream>>>(count, N_NODES);
        wt_kernel<<<64, 256, 0, stream>>>(W, Wt);
        zero_f4_kernel<<<(N_NODES * DIM / 4) / 256, 256, 0, stream>>>((float4*)out,
                                                                      N_NODES * DIM / 4);
        count_deg_kernel<<<N_EDGES / 256, 256, 0, stream>>>(ei, ew, count, deg);
        dinv_kernel<<<(N_NODES + 255) / 256, 256, 0, stream>>>(deg);
        scatter_kernel<<<(N_EDGES / 256) * 32, 256, 0, stream>>>(ei, ew, deg,
                                                                 (const float4*)x, out);
        final_kernel<<<N_NODES / 32, 256, 0, stream>>>(out, x, bias, deg, Wt, out);
    }
}

// Round 10
// 344.623 us; speedup vs baseline: 1.1122x; 1.0204x over previous
//
#include <hip/hip_runtime.h>

#define N_NODES 100000
#define N_EDGES 3200000
#define DIM 128

// hierarchical partition geometry
#define NB_C  98       // coarse buckets: dst>>10 (1024 nodes each)
#define CAP_C 36864    // avg 32653, sigma~181 -> +23 sigma
#define NB_F  1568     // fine buckets: 64 nodes each (NB_C*16)
#define CAP_F 2560     // avg 2041, sigma~45 -> +11 sigma
#define CAP   96       // legacy fallback bucket capacity

// payload u64: w_bits[63:32] | dst&1023 [26:17] | src [16:0]

typedef __attribute__((ext_vector_type(4))) float f32x4;
typedef __attribute__((ext_vector_type(8))) short s16x8;

// ============================ helpers ============================

__device__ __forceinline__ unsigned short f2bf(float f) {   // round-to-nearest-even
    unsigned u = __float_as_uint(f);
    return (unsigned short)((u + 0x7fffu + ((u >> 16) & 1u)) >> 16);
}

// ============================ small utility kernels ============================

__global__ __launch_bounds__(256) void zero_i_kernel(int* __restrict__ p, int n) {
    int i = blockIdx.x * 256 + threadIdx.x;
    if (i < n) p[i] = 0;
}

__global__ __launch_bounds__(256) void zero_f_kernel(float* __restrict__ p, int n) {
    int i = blockIdx.x * 256 + threadIdx.x;
    if (i < n) p[i] = 0.0f;
}

__global__ __launch_bounds__(256) void zero_u64_kernel(unsigned long long* __restrict__ p, int n) {
    int i = blockIdx.x * 256 + threadIdx.x;
    if (i < n) p[i] = 0ull;
}

__global__ __launch_bounds__(256) void zero_f4_kernel(float4* __restrict__ p, int n4) {
    int i = blockIdx.x * 256 + threadIdx.x;
    if (i < n4) p[i] = make_float4(0.f, 0.f, 0.f, 0.f);
}

__global__ __launch_bounds__(256) void dinv_kernel(float* __restrict__ deg) {
    int i = blockIdx.x * 256 + threadIdx.x;
    if (i < N_NODES) deg[i] = rsqrtf(deg[i] + 1.0f);
}

__global__ __launch_bounds__(256) void dinv_packed_kernel(const unsigned long long* __restrict__ packed,
                                                          float* __restrict__ dinv) {
    int i = blockIdx.x * 256 + threadIdx.x;
    if (i < N_NODES) {
        unsigned long long p = packed[i];
        float deg = (float)(p & 0xFFFFFFFFFFull) * (1.0f / 4294967296.0f);
        dinv[i] = rsqrtf(deg + 1.0f);
    }
}

__global__ __launch_bounds__(256) void wt_kernel(const float* __restrict__ W,
                                                 float* __restrict__ Wt) {
    int idx = blockIdx.x * 256 + threadIdx.x;
    int j = idx >> 7, k = idx & 127;
    Wt[k * 128 + j] = W[idx];
}

// ==================== prep: W -> MFMA B-fragment tables (hi/lo bf16) + fills ==
// Split precision: W = Wh + Wl with Wh = bf16(W), Wl = bf16(W - Wh).
// Fragment order for mfma_f32_16x16x32_bf16 B-operand:
//   idx = ((ct*4+ks)*64 + lane)*8 + j ; col = ct*16+(lane&15),
//   k = ks*32+(lane>>4)*8+j ; value = W[col][k]  (B[k][n] = W^T[k][n] = W[n][k])
// grid: [0,64) fragment build (16384 elems); [64,71) zero 1666 fill ints

__global__ __launch_bounds__(256) void prep_kernel(const float* __restrict__ W,
                                                   ushort* __restrict__ wf_hi,
                                                   ushort* __restrict__ wf_lo,
                                                   int* __restrict__ fills) {
    const int b = blockIdx.x;
    const int tid = threadIdx.x;
    if (b < 64) {
        int idx  = b * 256 + tid;           // [0,16384)
        int j    = idx & 7;
        int lane = (idx >> 3) & 63;
        int ks   = (idx >> 9) & 3;
        int ct   = idx >> 11;
        int col  = ct * 16 + (lane & 15);
        int k    = ks * 32 + ((lane >> 4) << 3) + j;
        float w  = W[col * 128 + k];
        unsigned short hb = f2bf(w);
        float rem = w - __uint_as_float((unsigned)hb << 16);
        wf_hi[idx] = hb;
        wf_lo[idx] = f2bf(rem);
    } else {
        int i = (b - 64) * 256 + tid;
        if (i < NB_C + NB_F) fills[i] = 0;
    }
}

// ==================== pass A1: edges -> 98 coarse buckets =====================
// THIS ROUND: LDS-staged coalesced output. Histogram + global-base phases
// unchanged (positions bit-identical); the store phase now writes payloads
// to a block-local sorted 32 KB LDS stage (+1B segid), then flushes with
// consecutive threads -> consecutive global addresses (~8 lines/wave-store
// vs ~64 scattered before). edc content is bit-identical; only store order
// changes.

__global__ __launch_bounds__(256) void partA1_kernel(const int* __restrict__ ei,
                                                     const float* __restrict__ ew,
                                                     int* __restrict__ fill_c,
                                                     unsigned long long* __restrict__ edc) {
    __shared__ int hist[NB_C];
    __shared__ int base[NB_C];
    __shared__ int lpref[NB_C + 1];
    __shared__ unsigned long long stage[4096];
    __shared__ unsigned char segid[4096];
    const int tid = threadIdx.x;
    const int blockbase = blockIdx.x * 4096;
    for (int i = tid; i < NB_C; i += 256) hist[i] = 0;
    __syncthreads();

    unsigned long long pay[16];
    unsigned meta[16];
#pragma unroll
    for (int i = 0; i < 16; ++i) {
        int e = blockbase + i * 256 + tid;
        meta[i] = 0xFFFFFFFFu;
        if (e < N_EDGES) {
            int src = ei[e];
            int dst = ei[N_EDGES + e];
            float w = ew[e];
            int cb = dst >> 10;
            int pos = atomicAdd(&hist[cb], 1);
            pay[i] = ((unsigned long long)__float_as_uint(w) << 32)
                   | ((unsigned)(dst & 1023) << 17) | (unsigned)src;
            meta[i] = ((unsigned)cb << 16) | (unsigned)pos;
        }
    }
    __syncthreads();
    for (int c = tid; c < NB_C; c += 256) {
        int cnt = hist[c];
        base[c] = (cnt > 0) ? atomicAdd(&fill_c[c], cnt) : 0;
    }
    if (tid == 0) {
        int run = 0;
#pragma unroll
        for (int c = 0; c < NB_C; ++c) { lpref[c] = run; run += hist[c]; }
        lpref[NB_C] = run;
    }
    __syncthreads();
#pragma unroll
    for (int i = 0; i < 16; ++i) {
        if (meta[i] != 0xFFFFFFFFu) {
            int cb = (int)(meta[i] >> 16);
            int slot = lpref[cb] + (int)(meta[i] & 0xFFFFu);
            stage[slot] = pay[i];
            segid[slot] = (unsigned char)cb;
        }
    }
    __syncthreads();
    const int total = lpref[NB_C];
#pragma unroll
    for (int r = 0; r < 16; ++r) {
        int i = r * 256 + tid;
        if (i < total) {
            int sid = segid[i];
            int g = base[sid] + (i - lpref[sid]);
            if (g < CAP_C)
                edc[(unsigned)sid * CAP_C + (unsigned)g] = stage[i];
        }
    }
}

// ==================== pass A2: coarse -> 16 fine sub-buckets each =============
// 9 slice-blocks per coarse bucket (9*4096 >= CAP_C).
// Same LDS-staged coalesced output as A1 (16 segments, ~2 KB each -> long
// coalesced runs). Positions bit-identical to R6/R9 form.

__global__ __launch_bounds__(256) void partA2_kernel(const int* __restrict__ fill_c,
                                                     const unsigned long long* __restrict__ edc,
                                                     int* __restrict__ fill_f,
                                                     unsigned long long* __restrict__ edf) {
    __shared__ int hist[16];
    __shared__ int base[16];
    __shared__ int lpref[17];
    __shared__ unsigned long long stage[4096];
    __shared__ unsigned char segid[4096];
    const int tid = threadIdx.x;
    const int cb = blockIdx.x / 9;
    const int lo = (blockIdx.x % 9) * 4096;
    const int cnt_c = min(fill_c[cb], CAP_C);
    const int hi = min(lo + 4096, cnt_c);
    if (tid < 16) hist[tid] = 0;
    __syncthreads();

    unsigned long long pay[16];
    unsigned meta[16];
#pragma unroll
    for (int i = 0; i < 16; ++i) {
        int idx = lo + i * 256 + tid;
        meta[i] = 0xFFFFFFFFu;
        if (idx < hi) {
            unsigned long long p = edc[(unsigned)cb * CAP_C + (unsigned)idx];
            int f = (int)((p >> 23) & 15);      // dst bits [6,10)
            int pos = atomicAdd(&hist[f], 1);
            pay[i] = p;
            meta[i] = ((unsigned)f << 16) | (unsigned)pos;
        }
    }
    __syncthreads();
    if (tid < 16) {
        int c = hist[tid];
        base[tid] = (c > 0) ? atomicAdd(&fill_f[cb * 16 + tid], c) : 0;
    }
    if (tid == 0) {
        int run = 0;
#pragma unroll
        for (int c = 0; c < 16; ++c) { lpref[c] = run; run += hist[c]; }
        lpref[16] = run;
    }
    __syncthreads();
#pragma unroll
    for (int i = 0; i < 16; ++i) {
        if (meta[i] != 0xFFFFFFFFu) {
            int f = (int)(meta[i] >> 16);
            int slot = lpref[f] + (int)(meta[i] & 0xFFFFu);
            stage[slot] = pay[i];
            segid[slot] = (unsigned char)f;
        }
    }
    __syncthreads();
    const int total = lpref[16];
#pragma unroll
    for (int r = 0; r < 16; ++r) {
        int i = r * 256 + tid;
        if (i < total) {
            int sid = segid[i];
            int g = base[sid] + (i - lpref[sid]);
            if (g < CAP_F)
                edf[((unsigned)(cb * 16 + sid)) * CAP_F + (unsigned)g] = stage[i];
        }
    }
}

// ==================== pass B: in-place CSR compaction + degree/dinv ===========
// one block per fine bucket (64 nodes); scatter window 20 KB = L2-resident.
// R9 form (static pay/meta, fused u64 count|deg atomic). UNCHANGED.

__global__ __launch_bounds__(256) void partB_kernel(const int* __restrict__ fill_f,
                                                    unsigned long long* __restrict__ edf,
                                                    float* __restrict__ dinv,
                                                    int* __restrict__ row_start,
                                                    int* __restrict__ row_cnt,
                                                    const float4* __restrict__ x4,
                                                    ushort4* __restrict__ xh4) {
    __shared__ unsigned long long hd[64];   // low32 = count, high32 = deg fx2^24
    __shared__ int pref[64];
    __shared__ float dinv_s[64];
    const int tid = threadIdx.x;
    const int fb = blockIdx.x;
    const int node_base = fb * 64;
    const int cnt = min(fill_f[fb], CAP_F);
    if (tid < 64) hd[tid] = 0ull;
    __syncthreads();

    unsigned long long pay[10];
    unsigned meta[10];
#pragma unroll
    for (int it = 0; it < 10; ++it) {       // CAP_F/256 = 10, static indices
        int idx = it * 256 + tid;
        meta[it] = 0xFFFFFFFFu;
        if (idx < cnt) {
            unsigned long long p = edf[(unsigned)fb * CAP_F + (unsigned)idx];
            int dl = (int)((p >> 17) & 63);
            float w = __uint_as_float((unsigned)(p >> 32));
            unsigned long long inc = 1ull |
                ((unsigned long long)(unsigned)(w * 16777216.0f + 0.5f) << 32);
            unsigned long long old = atomicAdd(&hd[dl], inc);
            pay[it] = p;
            meta[it] = ((unsigned)dl << 16) | (unsigned)(old & 0xFFFFull);
        }
    }
    __syncthreads();
    if (tid == 0) {
        int run = 0;
#pragma unroll
        for (int n = 0; n < 64; ++n) { pref[n] = run; run += (int)(hd[n] & 0xFFFFFFFFull); }
    }
    __syncthreads();
    if (tid < 64) {
        int node = node_base + tid;
        if (node < N_NODES) {
            float deg = (float)(unsigned)(hd[tid] >> 32) * (1.0f / 16777216.0f);
            float dv = rsqrtf(deg + 1.0f);
            dinv[node] = dv;
            dinv_s[tid] = dv;
            row_start[node] = fb * CAP_F + pref[tid];
            row_cnt[node] = (int)(hd[tid] & 0xFFFFFFFFull);
        }
    }
    // all reads completed before the barriers above -> safe in-place compaction
#pragma unroll
    for (int it = 0; it < 10; ++it) {
        if (meta[it] != 0xFFFFFFFFu) {
            int dl = (int)(meta[it] >> 16);
            edf[(unsigned)fb * CAP_F + (unsigned)(pref[dl] + (int)(meta[it] & 0xFFFFu))] = pay[it];
        }
    }
    __syncthreads();                        // dinv_s[] valid for all 64 rows
    // fused xscale: xh[node,:] = bf16(x[node,:] * dinv[node]) for owned rows
#pragma unroll
    for (int i = 0; i < 8; ++i) {
        int idx = i * 256 + tid;            // [0,2048): 64 rows x 32 float4
        int r = idx >> 5;
        int node = node_base + r;
        if (node < N_NODES) {
            float dv = dinv_s[r];
            float4 v = x4[(unsigned)node * 32u + (unsigned)(idx & 31)];
            ushort4 h;
            h.x = f2bf(v.x * dv); h.y = f2bf(v.y * dv);
            h.z = f2bf(v.z * dv); h.w = f2bf(v.w * dv);
            xh4[(unsigned)node * 32u + (unsigned)(idx & 31)] = h;
        }
    }
}

// ==================== gather over exact CSR runs, bf16 x (pre-scaled) ========
// R1 version, byte-for-byte (107 us verified): node-per-wave, register
// accumulators, 8-deep ping-pong prefetch pipeline. MSHR*latency-bound plateau.

__global__ __launch_bounds__(256) void gatherc_kernel(const int* __restrict__ row_start,
                                                      const int* __restrict__ row_cnt,
                                                      const unsigned long long* __restrict__ edf,
                                                      const float* __restrict__ dinv,
                                                      const unsigned* __restrict__ xh,
                                                      float2* __restrict__ agg2) {
    const int lane = threadIdx.x & 63;
    const int node = blockIdx.x * 4 + (threadIdx.x >> 6);

    const int cnt = row_cnt[node];
    const int start = row_start[node];
    float ax0 = 0.f, ay0 = 0.f, ax1 = 0.f, ay1 = 0.f;   // 4 independent FMA chains

    for (int b = 0; b < cnt; b += 64) {
        int idx = b + lane;
        const bool valid = idx < cnt;
        if (!valid) idx = cnt - 1;                      // clamp: cached re-read
        unsigned long long p = edf[(unsigned)(start + idx)];
        int msrc = (int)(p & 0x1FFFFull);
        float mw = valid ? __uint_as_float((unsigned)(p >> 32)) : 0.0f;  // zero-pad
        const int mcnt = min(64, cnt - b);
        const int ng = (mcnt + 7) >> 3;                 // 8-edge groups (padded)

        unsigned va[8], vb[8];

#define PREF(buf, JB)                                                          \
        _Pragma("unroll")                                                      \
        for (int j = 0; j < 8; ++j) {                                          \
            int s = __builtin_amdgcn_readlane(msrc, (JB) + j);                 \
            buf[j] = xh[(unsigned)s * 64u + (unsigned)lane];                   \
        }
#define CONSUME(buf, JB)                                                       \
        _Pragma("unroll")                                                      \
        for (int j = 0; j < 8; ++j) {                                          \
            float w = __int_as_float(                                          \
                __builtin_amdgcn_readlane(__float_as_int(mw), (JB) + j));      \
            if (j & 1) {                                                       \
                ax1 = fmaf(__uint_as_float(buf[j] << 16), w, ax1);             \
                ay1 = fmaf(__uint_as_float(buf[j] & 0xffff0000u), w, ay1);     \
            } else {                                                           \
                ax0 = fmaf(__uint_as_float(buf[j] << 16), w, ax0);             \
                ay0 = fmaf(__uint_as_float(buf[j] & 0xffff0000u), w, ay0);     \
            }                                                                  \
        }

        PREF(va, 0);
        int g = 0;
        for (; g + 2 < ng; g += 2) {
            PREF(vb, (g + 1) * 8);      // issue next group while consuming va
            CONSUME(va, g * 8);
            PREF(va, (g + 2) * 8);      // ping-pong back
            CONSUME(vb, (g + 1) * 8);
        }
        if (g + 1 < ng) {               // two groups remain
            PREF(vb, (g + 1) * 8);
            CONSUME(va, g * 8);
            CONSUME(vb, (g + 1) * 8);
        } else {                        // one group remains
            CONSUME(va, g * 8);
        }
#undef PREF
#undef CONSUME
    }

    float di = dinv[node];
    agg2[(unsigned)node * 64u + lane] = make_float2((ax0 + ax1) * di, (ay0 + ay1) * di);
}

// ==================== fallback kernels (f32 bucket / CSR / scatter) ===========

__global__ __launch_bounds__(256) void bucket_f32_kernel(const int* __restrict__ ei,
                                                         const float* __restrict__ ew,
                                                         unsigned long long* __restrict__ packed,
                                                         int2* __restrict__ ed) {
    int e = blockIdx.x * 256 + threadIdx.x;
    int src = ei[e];
    int dst = ei[N_EDGES + e];
    float w = ew[e];
    unsigned long long inc = (1ull << 40) | (unsigned long long)(w * 4294967296.0f);
    unsigned long long old = atomicAdd(&packed[dst], inc);
    unsigned slot = (unsigned)(old >> 40);
    if (slot < CAP) {
        ed[(unsigned)dst * CAP + slot] = make_int2(src, __float_as_int(w));
    }
}

__global__ __launch_bounds__(256) void gatherb_f32_kernel(const unsigned long long* __restrict__ packed,
                                                          const int2* __restrict__ ed,
                                                          const float* __restrict__ dinv,
                                                          const float2* __restrict__ x2,
                                                          float2* __restrict__ agg2) {
    const int wave = threadIdx.x >> 6;
    const int lane = threadIdx.x & 63;
    const int node = blockIdx.x * 4 + wave;

    int cnt = (int)(packed[node] >> 40);
    cnt = min(cnt, CAP);
    const unsigned base = (unsigned)node * CAP;
    float2 acc = make_float2(0.f, 0.f);

    for (int b = 0; b < cnt; b += 64) {
        int idx = b + lane;
        if (idx >= cnt) idx = cnt - 1;
        int2 my = ed[base + idx];
        float wmy = __int_as_float(my.y) * dinv[my.x];
        int m = min(64, cnt - b);
#pragma unroll 8
        for (int j = 0; j < m; ++j) {
            int s = __builtin_amdgcn_readlane(my.x, j);
            float w = __int_as_float(__builtin_amdgcn_readlane(__float_as_int(wmy), j));
            float2 v = x2[(unsigned)s * 64u + lane];
            acc.x = fmaf(v.x, w, acc.x); acc.y = fmaf(v.y, w, acc.y);
        }
    }
    float di = dinv[node];
    acc.x *= di; acc.y *= di;
    agg2[(unsigned)node * 64u + lane] = acc;
}

__global__ __launch_bounds__(256) void count_deg_kernel(const int* __restrict__ ei,
                                                        const float* __restrict__ ew,
                                                        int* __restrict__ count,
                                                        float* __restrict__ deg) {
    int e = blockIdx.x * 256 + threadIdx.x;
    int dst = ei[N_EDGES + e];
    atomicAdd(&count[dst], 1);
    atomicAdd(&deg[dst], ew[e]);
}

__global__ __launch_bounds__(256) void scatter_kernel(const int* __restrict__ ei,
                                                      const float* __restrict__ ew,
                                                      const float* __restrict__ dinv,
                                                      const float4* __restrict__ x4,
                                                      float* __restrict__ agg) {
    unsigned gid = blockIdx.x * 256u + threadIdx.x;
    unsigned e  = gid >> 5;
    unsigned f4 = gid & 31u;
    int src = ei[e];
    int dst = ei[N_EDGES + e];
    float w = dinv[src] * ew[e] * dinv[dst];
    float4 v = x4[(unsigned)src * 32u + f4];
    float* o = agg + ((unsigned)dst * 128u + f4 * 4u);
    atomicAdd(o + 0, v.x * w);
    atomicAdd(o + 1, v.y * w);
    atomicAdd(o + 2, v.z * w);
    atomicAdd(o + 3, v.w * w);
}

// ============================ final: split-bf16 MFMA GEMM + epilogue ==========
// out[i,:] = relu( (agg[i,:] + x[i,:]*dinv[i]^2) @ W^T + bias ) + x[i,:]
// A = Ah+Al, W = Wh+Wl (bf16 splits); A@W ~= Ah@Wh + Ah@Wl + Al@Wh
// (error ~2^-17 rel, keeps f32-grade absmax). UNCHANGED (R6 form).

__global__ __launch_bounds__(256) void final_mfma_kernel(const float* __restrict__ agg_in,
                                                         const float* __restrict__ x,
                                                         const float* __restrict__ bias,
                                                         const float* __restrict__ dinv,
                                                         const ushort* __restrict__ wf_hi,
                                                         const ushort* __restrict__ wf_lo,
                                                         float* __restrict__ out) {
    __shared__ ushort sh_hi[16384];
    __shared__ ushort sh_lo[16384];
    const int tid = threadIdx.x;
    {
        const float4* sh4 = (const float4*)wf_hi;
        const float4* sl4 = (const float4*)wf_lo;
        float4* dh = (float4*)sh_hi;
        float4* dl = (float4*)sh_lo;
#pragma unroll
        for (int i = 0; i < 8; ++i) {
            dh[i * 256 + tid] = sh4[i * 256 + tid];
            dl[i * 256 + tid] = sl4[i * 256 + tid];
        }
    }
    __syncthreads();

    const int wave = tid >> 6;
    const int lane = tid & 63;
    const int r0 = blockIdx.x * 64 + wave * 16;
    const int mrow = lane & 15;          // A row within tile
    const int kg = lane >> 4;            // k-group
    const int arow = min(r0 + mrow, N_NODES - 1);   // clamped (tail block)
    const float di = dinv[arow];
    const float di2 = di * di;

    // A-fragments: lane holds 8 k-contiguous elems at k = ks*32 + kg*8 + j
    s16x8 ah[4], al[4];
#pragma unroll
    for (int ks = 0; ks < 4; ++ks) {
        const float* ap = agg_in + (unsigned)arow * 128u + ks * 32 + kg * 8;
        const float* xp = x      + (unsigned)arow * 128u + ks * 32 + kg * 8;
        float4 a0 = *(const float4*)ap;
        float4 a1 = *(const float4*)(ap + 4);
        float4 x0 = *(const float4*)xp;
        float4 x1 = *(const float4*)(xp + 4);
        float v[8] = {a0.x + x0.x * di2, a0.y + x0.y * di2,
                      a0.z + x0.z * di2, a0.w + x0.w * di2,
                      a1.x + x1.x * di2, a1.y + x1.y * di2,
                      a1.z + x1.z * di2, a1.w + x1.w * di2};
        s16x8 h, l;
#pragma unroll
        for (int j = 0; j < 8; ++j) {
            unsigned short hb = f2bf(v[j]);
            h[j] = (short)hb;
            l[j] = (short)f2bf(v[j] - __uint_as_float((unsigned)hb << 16));
        }
        ah[ks] = h; al[ks] = l;
    }

#pragma unroll
    for (int ct = 0; ct < 8; ++ct) {
        f32x4 acc = {0.f, 0.f, 0.f, 0.f};
#pragma unroll
        for (int ks = 0; ks < 4; ++ks) {
            const int fo = ((ct * 4 + ks) * 64 + lane) * 8;
            s16x8 bh = *(const s16x8*)&sh_hi[fo];
            s16x8 bl = *(const s16x8*)&sh_lo[fo];
            acc = __builtin_amdgcn_mfma_f32_16x16x32_bf16(ah[ks], bh, acc, 0, 0, 0);
            acc = __builtin_amdgcn_mfma_f32_16x16x32_bf16(ah[ks], bl, acc, 0, 0, 0);
            acc = __builtin_amdgcn_mfma_f32_16x16x32_bf16(al[ks], bh, acc, 0, 0, 0);
        }
        // C/D layout (m89-verified): col = lane&15, row = (lane>>4)*4 + reg
        const int col = ct * 16 + mrow;
        const float bv = bias[col];
#pragma unroll
        for (int v = 0; v < 4; ++v) {
            const int row = r0 + kg * 4 + v;
            if (row < N_NODES) {
                float o = fmaxf(acc[v] + bv, 0.f) + x[(unsigned)row * 128u + col];
                out[(unsigned)row * 128u + col] = o;
            }
        }
    }
}

// ============================ legacy vector final (fallback paths) ============

__global__ __launch_bounds__(256) void final_kernel(const float* __restrict__ agg_in,
                                                    const float* __restrict__ x,
                                                    const float* __restrict__ bias,
                                                    const float* __restrict__ dinv,
                                                    const float* __restrict__ Wt,
                                                    float* __restrict__ out) {
    __shared__ float sh_wt[16384];
    const int tid = threadIdx.x;
    {
        const float4* s4 = (const float4*)Wt;
        float4* d4 = (float4*)sh_wt;
#pragma unroll
        for (int i = 0; i < 16; ++i) d4[i * 256 + tid] = s4[i * 256 + tid];
    }
    __syncthreads();

    const int wave = tid >> 6;
    const int lane = tid & 63;
    const int rowbase = blockIdx.x * 32 + wave * 8;

    float areg[16];
#pragma unroll
    for (int r = 0; r < 8; ++r) {
        int row = rowbase + r;
        float di = dinv[row];
        float di2 = di * di;
        int base = row * 128;
        areg[2 * r]     = agg_in[base + lane]      + x[base + lane]      * di2;
        areg[2 * r + 1] = agg_in[base + 64 + lane] + x[base + 64 + lane] * di2;
    }

    float acc0[8], acc1[8];
#pragma unroll
    for (int r = 0; r < 8; ++r) { acc0[r] = 0.f; acc1[r] = 0.f; }

    const float2* wt2 = (const float2*)sh_wt;

#pragma unroll
    for (int kh = 0; kh < 2; ++kh) {
#pragma unroll 16
        for (int kk = 0; kk < 64; ++kk) {
            int k = kh * 64 + kk;
            float2 w = wt2[k * 64 + lane];
#pragma unroll
            for (int r = 0; r < 8; ++r) {
                float ak = __uint_as_float(
                    __builtin_amdgcn_readlane(__float_as_uint(areg[2 * r + kh]), kk));
                acc0[r] = fmaf(ak, w.x, acc0[r]);
                acc1[r] = fmaf(ak, w.y, acc1[r]);
            }
        }
    }

    float2 b = ((const float2*)bias)[lane];
#pragma unroll
    for (int r = 0; r < 8; ++r) {
        int row = rowbase + r;
        float2 xr = ((const float2*)x)[row * 64 + lane];
        float v0 = fmaxf(acc0[r] + b.x, 0.f) + xr.x;
        float v1 = fmaxf(acc1[r] + b.y, 0.f) + xr.y;
        ((float2*)out)[row * 64 + lane] = make_float2(v0, v1);
    }
}

// ===============================================================================

extern "C" void kernel_launch(void* const* d_in, const int* in_sizes, int n_in,
                              void* d_out, int out_size, void* d_ws, size_t ws_size,
                              hipStream_t stream) {
    const float* x    = (const float*)d_in[0];
    const float* W    = (const float*)d_in[1];
    const float* bias = (const float*)d_in[2];
    const float* ew   = (const float*)d_in[3];
    const int*   ei   = (const int*)d_in[4];
    float* out = (float*)d_out;
    char* ws = (char*)d_ws;

    // ---------- primary layout (hierarchical partition) ----------
    // xh bf16[N*128]       [0, 25600000)
    // Wfrag hi/lo ushort   [25600000, 25665536)
    // dinv f32[N]          [25665536, 26065536)
    // row_start int[N]     [26065536, 26465536)
    // row_cnt int[N]       [26465536, 26865536)
    // fill_c int[98]       [26865536, ...) contiguous with fill_f int[1568]
    // edc u64[98*36864]    [26872256, 55773632)
    // edf u64[1568*2560]   [55773632, 87886272)
    unsigned short* xhA  = (unsigned short*)ws;
    ushort* wfhi     = (ushort*)(ws + 25600000);
    ushort* wflo     = wfhi + 16384;
    float* dinvA     = (float*)(ws + 25665536);
    int*   row_start = (int*)  (ws + 26065536);
    int*   row_cnt   = (int*)  (ws + 26465536);
    int*   fill_c    = (int*)  (ws + 26865536);
    int*   fill_f    = fill_c + NB_C;
    unsigned long long* edc = (unsigned long long*)(ws + 26872256);
    unsigned long long* edf = (unsigned long long*)(ws + 55773632);
    const size_t WS_PART = 87886272ull;

    // ---------- fallback layout (round-3 bucket) ----------
    unsigned long long* packed = (unsigned long long*)ws;
    float* dinvB = (float*)(ws + 800000);
    float* WtB   = (float*)(ws + 1200000);
    int2*  edB   = (int2*)(ws + 1265536);
    const size_t WS_BUCKET = 1265536ull + (size_t)N_NODES * CAP * 8ull;   // ~78.1 MB

    if (ws_size >= WS_PART) {
        prep_kernel<<<71, 256, 0, stream>>>(W, wfhi, wflo, fill_c);
        partA1_kernel<<<(N_EDGES + 4095) / 4096, 256, 0, stream>>>(ei, ew, fill_c, edc);
        partA2_kernel<<<NB_C * 9, 256, 0, stream>>>(fill_c, edc, fill_f, edf);
        partB_kernel<<<NB_F, 256, 0, stream>>>(fill_f, edf, dinvA, row_start, row_cnt,
                                               (const float4*)x, (ushort4*)xhA);
        gatherc_kernel<<<N_NODES / 4, 256, 0, stream>>>(row_start, row_cnt, edf, dinvA,
                                                        (const unsigned*)xhA, (float2*)out);
        final_mfma_kernel<<<(N_NODES + 63) / 64, 256, 0, stream>>>(out, x, bias, dinvA,
                                                                   wfhi, wflo, out);
    } else if (ws_size >= WS_BUCKET) {
        zero_u64_kernel<<<(N_NODES + 255) / 256, 256, 0, stream>>>(packed, N_NODES);
        wt_kernel<<<64, 256, 0, stream>>>(W, WtB);
        bucket_f32_kernel<<<N_EDGES / 256, 256, 0, stream>>>(ei, ew, packed, edB);
        dinv_packed_kernel<<<(N_NODES + 255) / 256, 256, 0, stream>>>(packed, dinvB);
        gatherb_f32_kernel<<<N_NODES / 4, 256, 0, stream>>>(packed, edB, dinvB,
                                                            (const float2*)x, (float2*)out);
        final_kernel<<<N_NODES / 32, 256, 0, stream>>>(out, x, bias, dinvB, WtB, out);
    } else {
        float* deg   = (float*)(ws);
        float* Wt    = (float*)(ws + 400000);
        int*   count = (int*)  (ws + 465536);
        zero_f_kernel<<<(N_NODES + 255) / 256, 256, 0, stream>>>(deg, N_NODES);
        zero_i_kernel<<<(N_NODES + 255) / 256, 256, 0, stream>>>(count, N_NODES);
        wt_kernel<<<64, 256, 0, stream>>>(W, Wt);
        zero_f4_kernel<<<(N_NODES * DIM / 4) / 256, 256, 0, stream>>>((float4*)out,
                                                                      N_NODES * DIM / 4);
        count_deg_kernel<<<N_EDGES / 256, 256, 0, stream>>>(ei, ew, count, deg);
        dinv_kernel<<<(N_NODES + 255) / 256, 256, 0, stream>>>(deg);
        scatter_kernel<<<(N_EDGES / 256) * 32, 256, 0, stream>>>(ei, ew, deg,
                                                                 (const float4*)x, out);
        final_kernel<<<N_NODES / 32, 256, 0, stream>>>(out, x, bias, deg, Wt, out);
    }
}

// Round 11
// 343.514 us; speedup vs baseline: 1.1158x; 1.0032x over previous
//
#include <hip/hip_runtime.h>

#define N_NODES 100000
#define N_EDGES 3200000
#define DIM 128

// hierarchical partition geometry
#define NB_C  98       // coarse buckets: dst>>10 (1024 nodes each)
#define CAP_C 36864    // avg 32653, sigma~181 -> +23 sigma
#define NB_F  1568     // fine buckets: 64 nodes each (NB_C*16)
#define CAP_F 2560     // avg 2041, sigma~45 -> +11 sigma
#define CAP   96       // legacy fallback bucket capacity

// payload u64: w_bits[63:32] | dst&1023 [26:17] | src [16:0]

typedef __attribute__((ext_vector_type(4))) float f32x4;
typedef __attribute__((ext_vector_type(8))) short s16x8;

// ============================ helpers ============================

__device__ __forceinline__ unsigned short f2bf(float f) {   // round-to-nearest-even
    unsigned u = __float_as_uint(f);
    return (unsigned short)((u + 0x7fffu + ((u >> 16) & 1u)) >> 16);
}

// ============================ small utility kernels ============================

__global__ __launch_bounds__(256) void zero_i_kernel(int* __restrict__ p, int n) {
    int i = blockIdx.x * 256 + threadIdx.x;
    if (i < n) p[i] = 0;
}

__global__ __launch_bounds__(256) void zero_f_kernel(float* __restrict__ p, int n) {
    int i = blockIdx.x * 256 + threadIdx.x;
    if (i < n) p[i] = 0.0f;
}

__global__ __launch_bounds__(256) void zero_u64_kernel(unsigned long long* __restrict__ p, int n) {
    int i = blockIdx.x * 256 + threadIdx.x;
    if (i < n) p[i] = 0ull;
}

__global__ __launch_bounds__(256) void zero_f4_kernel(float4* __restrict__ p, int n4) {
    int i = blockIdx.x * 256 + threadIdx.x;
    if (i < n4) p[i] = make_float4(0.f, 0.f, 0.f, 0.f);
}

__global__ __launch_bounds__(256) void dinv_kernel(float* __restrict__ deg) {
    int i = blockIdx.x * 256 + threadIdx.x;
    if (i < N_NODES) deg[i] = rsqrtf(deg[i] + 1.0f);
}

__global__ __launch_bounds__(256) void dinv_packed_kernel(const unsigned long long* __restrict__ packed,
                                                          float* __restrict__ dinv) {
    int i = blockIdx.x * 256 + threadIdx.x;
    if (i < N_NODES) {
        unsigned long long p = packed[i];
        float deg = (float)(p & 0xFFFFFFFFFFull) * (1.0f / 4294967296.0f);
        dinv[i] = rsqrtf(deg + 1.0f);
    }
}

__global__ __launch_bounds__(256) void wt_kernel(const float* __restrict__ W,
                                                 float* __restrict__ Wt) {
    int idx = blockIdx.x * 256 + threadIdx.x;
    int j = idx >> 7, k = idx & 127;
    Wt[k * 128 + j] = W[idx];
}

// ==================== prep: W -> MFMA B-fragment tables (hi/lo bf16) + fills ==
// Split precision: W = Wh + Wl with Wh = bf16(W), Wl = bf16(W - Wh).
// Fragment order for mfma_f32_16x16x32_bf16 B-operand:
//   idx = ((ct*4+ks)*64 + lane)*8 + j ; col = ct*16+(lane&15),
//   k = ks*32+(lane>>4)*8+j ; value = W[col][k]  (B[k][n] = W^T[k][n] = W[n][k])
// grid: [0,64) fragment build (16384 elems); [64,71) zero 1666 fill ints

__global__ __launch_bounds__(256) void prep_kernel(const float* __restrict__ W,
                                                   ushort* __restrict__ wf_hi,
                                                   ushort* __restrict__ wf_lo,
                                                   int* __restrict__ fills) {
    const int b = blockIdx.x;
    const int tid = threadIdx.x;
    if (b < 64) {
        int idx  = b * 256 + tid;           // [0,16384)
        int j    = idx & 7;
        int lane = (idx >> 3) & 63;
        int ks   = (idx >> 9) & 3;
        int ct   = idx >> 11;
        int col  = ct * 16 + (lane & 15);
        int k    = ks * 32 + ((lane >> 4) << 3) + j;
        float w  = W[col * 128 + k];
        unsigned short hb = f2bf(w);
        float rem = w - __uint_as_float((unsigned)hb << 16);
        wf_hi[idx] = hb;
        wf_lo[idx] = f2bf(rem);
    } else {
        int i = (b - 64) * 256 + tid;
        if (i < NB_C + NB_F) fills[i] = 0;
    }
}

// ==================== pass A1: edges -> 98 coarse buckets =====================
// R10 form: LDS-staged coalesced output (positions bit-identical; store
// order coalesced). UNCHANGED this round.

__global__ __launch_bounds__(256) void partA1_kernel(const int* __restrict__ ei,
                                                     const float* __restrict__ ew,
                                                     int* __restrict__ fill_c,
                                                     unsigned long long* __restrict__ edc) {
    __shared__ int hist[NB_C];
    __shared__ int base[NB_C];
    __shared__ int lpref[NB_C + 1];
    __shared__ unsigned long long stage[4096];
    __shared__ unsigned char segid[4096];
    const int tid = threadIdx.x;
    const int blockbase = blockIdx.x * 4096;
    for (int i = tid; i < NB_C; i += 256) hist[i] = 0;
    __syncthreads();

    unsigned long long pay[16];
    unsigned meta[16];
#pragma unroll
    for (int i = 0; i < 16; ++i) {
        int e = blockbase + i * 256 + tid;
        meta[i] = 0xFFFFFFFFu;
        if (e < N_EDGES) {
            int src = ei[e];
            int dst = ei[N_EDGES + e];
            float w = ew[e];
            int cb = dst >> 10;
            int pos = atomicAdd(&hist[cb], 1);
            pay[i] = ((unsigned long long)__float_as_uint(w) << 32)
                   | ((unsigned)(dst & 1023) << 17) | (unsigned)src;
            meta[i] = ((unsigned)cb << 16) | (unsigned)pos;
        }
    }
    __syncthreads();
    for (int c = tid; c < NB_C; c += 256) {
        int cnt = hist[c];
        base[c] = (cnt > 0) ? atomicAdd(&fill_c[c], cnt) : 0;
    }
    if (tid == 0) {
        int run = 0;
#pragma unroll
        for (int c = 0; c < NB_C; ++c) { lpref[c] = run; run += hist[c]; }
        lpref[NB_C] = run;
    }
    __syncthreads();
#pragma unroll
    for (int i = 0; i < 16; ++i) {
        if (meta[i] != 0xFFFFFFFFu) {
            int cb = (int)(meta[i] >> 16);
            int slot = lpref[cb] + (int)(meta[i] & 0xFFFFu);
            stage[slot] = pay[i];
            segid[slot] = (unsigned char)cb;
        }
    }
    __syncthreads();
    const int total = lpref[NB_C];
#pragma unroll
    for (int r = 0; r < 16; ++r) {
        int i = r * 256 + tid;
        if (i < total) {
            int sid = segid[i];
            int g = base[sid] + (i - lpref[sid]);
            if (g < CAP_C)
                edc[(unsigned)sid * CAP_C + (unsigned)g] = stage[i];
        }
    }
}

// ==================== pass A2: coarse -> 16 fine sub-buckets each =============
// 9 slice-blocks per coarse bucket (9*4096 >= CAP_C).
// R10 form: LDS-staged coalesced output. UNCHANGED this round.

__global__ __launch_bounds__(256) void partA2_kernel(const int* __restrict__ fill_c,
                                                     const unsigned long long* __restrict__ edc,
                                                     int* __restrict__ fill_f,
                                                     unsigned long long* __restrict__ edf) {
    __shared__ int hist[16];
    __shared__ int base[16];
    __shared__ int lpref[17];
    __shared__ unsigned long long stage[4096];
    __shared__ unsigned char segid[4096];
    const int tid = threadIdx.x;
    const int cb = blockIdx.x / 9;
    const int lo = (blockIdx.x % 9) * 4096;
    const int cnt_c = min(fill_c[cb], CAP_C);
    const int hi = min(lo + 4096, cnt_c);
    if (tid < 16) hist[tid] = 0;
    __syncthreads();

    unsigned long long pay[16];
    unsigned meta[16];
#pragma unroll
    for (int i = 0; i < 16; ++i) {
        int idx = lo + i * 256 + tid;
        meta[i] = 0xFFFFFFFFu;
        if (idx < hi) {
            unsigned long long p = edc[(unsigned)cb * CAP_C + (unsigned)idx];
            int f = (int)((p >> 23) & 15);      // dst bits [6,10)
            int pos = atomicAdd(&hist[f], 1);
            pay[i] = p;
            meta[i] = ((unsigned)f << 16) | (unsigned)pos;
        }
    }
    __syncthreads();
    if (tid < 16) {
        int c = hist[tid];
        base[tid] = (c > 0) ? atomicAdd(&fill_f[cb * 16 + tid], c) : 0;
    }
    if (tid == 0) {
        int run = 0;
#pragma unroll
        for (int c = 0; c < 16; ++c) { lpref[c] = run; run += hist[c]; }
        lpref[16] = run;
    }
    __syncthreads();
#pragma unroll
    for (int i = 0; i < 16; ++i) {
        if (meta[i] != 0xFFFFFFFFu) {
            int f = (int)(meta[i] >> 16);
            int slot = lpref[f] + (int)(meta[i] & 0xFFFFu);
            stage[slot] = pay[i];
            segid[slot] = (unsigned char)f;
        }
    }
    __syncthreads();
    const int total = lpref[16];
#pragma unroll
    for (int r = 0; r < 16; ++r) {
        int i = r * 256 + tid;
        if (i < total) {
            int sid = segid[i];
            int g = base[sid] + (i - lpref[sid]);
            if (g < CAP_F)
                edf[((unsigned)(cb * 16 + sid)) * CAP_F + (unsigned)g] = stage[i];
        }
    }
}

// ==================== pass B: in-place CSR compaction + degree/dinv ===========
// one block per fine bucket (64 nodes); scatter window 20 KB = L2-resident.
// R9 form (static pay/meta, fused u64 count|deg atomic). UNCHANGED.

__global__ __launch_bounds__(256) void partB_kernel(const int* __restrict__ fill_f,
                                                    unsigned long long* __restrict__ edf,
                                                    float* __restrict__ dinv,
                                                    int* __restrict__ row_start,
                                                    int* __restrict__ row_cnt,
                                                    const float4* __restrict__ x4,
                                                    ushort4* __restrict__ xh4) {
    __shared__ unsigned long long hd[64];   // low32 = count, high32 = deg fx2^24
    __shared__ int pref[64];
    __shared__ float dinv_s[64];
    const int tid = threadIdx.x;
    const int fb = blockIdx.x;
    const int node_base = fb * 64;
    const int cnt = min(fill_f[fb], CAP_F);
    if (tid < 64) hd[tid] = 0ull;
    __syncthreads();

    unsigned long long pay[10];
    unsigned meta[10];
#pragma unroll
    for (int it = 0; it < 10; ++it) {       // CAP_F/256 = 10, static indices
        int idx = it * 256 + tid;
        meta[it] = 0xFFFFFFFFu;
        if (idx < cnt) {
            unsigned long long p = edf[(unsigned)fb * CAP_F + (unsigned)idx];
            int dl = (int)((p >> 17) & 63);
            float w = __uint_as_float((unsigned)(p >> 32));
            unsigned long long inc = 1ull |
                ((unsigned long long)(unsigned)(w * 16777216.0f + 0.5f) << 32);
            unsigned long long old = atomicAdd(&hd[dl], inc);
            pay[it] = p;
            meta[it] = ((unsigned)dl << 16) | (unsigned)(old & 0xFFFFull);
        }
    }
    __syncthreads();
    if (tid == 0) {
        int run = 0;
#pragma unroll
        for (int n = 0; n < 64; ++n) { pref[n] = run; run += (int)(hd[n] & 0xFFFFFFFFull); }
    }
    __syncthreads();
    if (tid < 64) {
        int node = node_base + tid;
        if (node < N_NODES) {
            float deg = (float)(unsigned)(hd[tid] >> 32) * (1.0f / 16777216.0f);
            float dv = rsqrtf(deg + 1.0f);
            dinv[node] = dv;
            dinv_s[tid] = dv;
            row_start[node] = fb * CAP_F + pref[tid];
            row_cnt[node] = (int)(hd[tid] & 0xFFFFFFFFull);
        }
    }
    // all reads completed before the barriers above -> safe in-place compaction
#pragma unroll
    for (int it = 0; it < 10; ++it) {
        if (meta[it] != 0xFFFFFFFFu) {
            int dl = (int)(meta[it] >> 16);
            edf[(unsigned)fb * CAP_F + (unsigned)(pref[dl] + (int)(meta[it] & 0xFFFFu))] = pay[it];
        }
    }
    __syncthreads();                        // dinv_s[] valid for all 64 rows
    // fused xscale: xh[node,:] = bf16(x[node,:] * dinv[node]) for owned rows
#pragma unroll
    for (int i = 0; i < 8; ++i) {
        int idx = i * 256 + tid;            // [0,2048): 64 rows x 32 float4
        int r = idx >> 5;
        int node = node_base + r;
        if (node < N_NODES) {
            float dv = dinv_s[r];
            float4 v = x4[(unsigned)node * 32u + (unsigned)(idx & 31)];
            ushort4 h;
            h.x = f2bf(v.x * dv); h.y = f2bf(v.y * dv);
            h.z = f2bf(v.z * dv); h.w = f2bf(v.w * dv);
            xh4[(unsigned)node * 32u + (unsigned)(idx & 31)] = h;
        }
    }
}

// ==================== gather over exact CSR runs, bf16 x (pre-scaled) ========
// R1 version, byte-for-byte (107 us verified): node-per-wave, register
// accumulators, 8-deep ping-pong prefetch pipeline. MSHR*latency-bound plateau.

__global__ __launch_bounds__(256) void gatherc_kernel(const int* __restrict__ row_start,
                                                      const int* __restrict__ row_cnt,
                                                      const unsigned long long* __restrict__ edf,
                                                      const float* __restrict__ dinv,
                                                      const unsigned* __restrict__ xh,
                                                      float2* __restrict__ agg2) {
    const int lane = threadIdx.x & 63;
    const int node = blockIdx.x * 4 + (threadIdx.x >> 6);

    const int cnt = row_cnt[node];
    const int start = row_start[node];
    float ax0 = 0.f, ay0 = 0.f, ax1 = 0.f, ay1 = 0.f;   // 4 independent FMA chains

    for (int b = 0; b < cnt; b += 64) {
        int idx = b + lane;
        const bool valid = idx < cnt;
        if (!valid) idx = cnt - 1;                      // clamp: cached re-read
        unsigned long long p = edf[(unsigned)(start + idx)];
        int msrc = (int)(p & 0x1FFFFull);
        float mw = valid ? __uint_as_float((unsigned)(p >> 32)) : 0.0f;  // zero-pad
        const int mcnt = min(64, cnt - b);
        const int ng = (mcnt + 7) >> 3;                 // 8-edge groups (padded)

        unsigned va[8], vb[8];

#define PREF(buf, JB)                                                          \
        _Pragma("unroll")                                                      \
        for (int j = 0; j < 8; ++j) {                                          \
            int s = __builtin_amdgcn_readlane(msrc, (JB) + j);                 \
            buf[j] = xh[(unsigned)s * 64u + (unsigned)lane];                   \
        }
#define CONSUME(buf, JB)                                                       \
        _Pragma("unroll")                                                      \
        for (int j = 0; j < 8; ++j) {                                          \
            float w = __int_as_float(                                          \
                __builtin_amdgcn_readlane(__float_as_int(mw), (JB) + j));      \
            if (j & 1) {                                                       \
                ax1 = fmaf(__uint_as_float(buf[j] << 16), w, ax1);             \
                ay1 = fmaf(__uint_as_float(buf[j] & 0xffff0000u), w, ay1);     \
            } else {                                                           \
                ax0 = fmaf(__uint_as_float(buf[j] << 16), w, ax0);             \
                ay0 = fmaf(__uint_as_float(buf[j] & 0xffff0000u), w, ay0);     \
            }                                                                  \
        }

        PREF(va, 0);
        int g = 0;
        for (; g + 2 < ng; g += 2) {
            PREF(vb, (g + 1) * 8);      // issue next group while consuming va
            CONSUME(va, g * 8);
            PREF(va, (g + 2) * 8);      // ping-pong back
            CONSUME(vb, (g + 1) * 8);
        }
        if (g + 1 < ng) {               // two groups remain
            PREF(vb, (g + 1) * 8);
            CONSUME(va, g * 8);
            CONSUME(vb, (g + 1) * 8);
        } else {                        // one group remains
            CONSUME(va, g * 8);
        }
#undef PREF
#undef CONSUME
    }

    float di = dinv[node];
    agg2[(unsigned)node * 64u + lane] = make_float2((ax0 + ax1) * di, (ay0 + ay1) * di);
}

// ==================== fallback kernels (f32 bucket / CSR / scatter) ===========

__global__ __launch_bounds__(256) void bucket_f32_kernel(const int* __restrict__ ei,
                                                         const float* __restrict__ ew,
                                                         unsigned long long* __restrict__ packed,
                                                         int2* __restrict__ ed) {
    int e = blockIdx.x * 256 + threadIdx.x;
    int src = ei[e];
    int dst = ei[N_EDGES + e];
    float w = ew[e];
    unsigned long long inc = (1ull << 40) | (unsigned long long)(w * 4294967296.0f);
    unsigned long long old = atomicAdd(&packed[dst], inc);
    unsigned slot = (unsigned)(old >> 40);
    if (slot < CAP) {
        ed[(unsigned)dst * CAP + slot] = make_int2(src, __float_as_int(w));
    }
}

__global__ __launch_bounds__(256) void gatherb_f32_kernel(const unsigned long long* __restrict__ packed,
                                                          const int2* __restrict__ ed,
                                                          const float* __restrict__ dinv,
                                                          const float2* __restrict__ x2,
                                                          float2* __restrict__ agg2) {
    const int wave = threadIdx.x >> 6;
    const int lane = threadIdx.x & 63;
    const int node = blockIdx.x * 4 + wave;

    int cnt = (int)(packed[node] >> 40);
    cnt = min(cnt, CAP);
    const unsigned base = (unsigned)node * CAP;
    float2 acc = make_float2(0.f, 0.f);

    for (int b = 0; b < cnt; b += 64) {
        int idx = b + lane;
        if (idx >= cnt) idx = cnt - 1;
        int2 my = ed[base + idx];
        float wmy = __int_as_float(my.y) * dinv[my.x];
        int m = min(64, cnt - b);
#pragma unroll 8
        for (int j = 0; j < m; ++j) {
            int s = __builtin_amdgcn_readlane(my.x, j);
            float w = __int_as_float(__builtin_amdgcn_readlane(__float_as_int(wmy), j));
            float2 v = x2[(unsigned)s * 64u + lane];
            acc.x = fmaf(v.x, w, acc.x); acc.y = fmaf(v.y, w, acc.y);
        }
    }
    float di = dinv[node];
    acc.x *= di; acc.y *= di;
    agg2[(unsigned)node * 64u + lane] = acc;
}

__global__ __launch_bounds__(256) void count_deg_kernel(const int* __restrict__ ei,
                                                        const float* __restrict__ ew,
                                                        int* __restrict__ count,
                                                        float* __restrict__ deg) {
    int e = blockIdx.x * 256 + threadIdx.x;
    int dst = ei[N_EDGES + e];
    atomicAdd(&count[dst], 1);
    atomicAdd(&deg[dst], ew[e]);
}

__global__ __launch_bounds__(256) void scatter_kernel(const int* __restrict__ ei,
                                                      const float* __restrict__ ew,
                                                      const float* __restrict__ dinv,
                                                      const float4* __restrict__ x4,
                                                      float* __restrict__ agg) {
    unsigned gid = blockIdx.x * 256u + threadIdx.x;
    unsigned e  = gid >> 5;
    unsigned f4 = gid & 31u;
    int src = ei[e];
    int dst = ei[N_EDGES + e];
    float w = dinv[src] * ew[e] * dinv[dst];
    float4 v = x4[(unsigned)src * 32u + f4];
    float* o = agg + ((unsigned)dst * 128u + f4 * 4u);
    atomicAdd(o + 0, v.x * w);
    atomicAdd(o + 1, v.y * w);
    atomicAdd(o + 2, v.z * w);
    atomicAdd(o + 3, v.w * w);
}

// ============================ final: split-bf16 MFMA GEMM + epilogue ==========
// out[i,:] = relu( (agg[i,:] + x[i,:]*dinv[i]^2) @ W^T + bias ) + x[i,:]
// A = Ah+Al, W = Wh+Wl (bf16 splits); A@W ~= Ah@Wh + Ah@Wl + Al@Wh.
// THIS ROUND (isolated change): B-fragments streamed DIRECTLY from the
// global 64 KB wf tables (L2-resident, same for every block) instead of
// LDS staging. The R6 form's 64 KB LDS capped occupancy at 2 blocks/CU
// (8 waves/CU) -> latency-bound A-loads + 3 sequential occupancy rounds.
// No LDS -> VGPR-limited occupancy (~4x), loads fully coalesced 1KB/wave.
// MFMA order unchanged -> bit-identical output.

__global__ __launch_bounds__(256) void final_mfma_kernel(const float* __restrict__ agg_in,
                                                         const float* __restrict__ x,
                                                         const float* __restrict__ bias,
                                                         const float* __restrict__ dinv,
                                                         const ushort* __restrict__ wf_hi,
                                                         const ushort* __restrict__ wf_lo,
                                                         float* __restrict__ out) {
    const int tid = threadIdx.x;
    const int wave = tid >> 6;
    const int lane = tid & 63;
    const int r0 = blockIdx.x * 64 + wave * 16;
    const int mrow = lane & 15;          // A row within tile
    const int kg = lane >> 4;            // k-group
    const int arow = min(r0 + mrow, N_NODES - 1);   // clamped (tail block)
    const float di = dinv[arow];
    const float di2 = di * di;

    // A-fragments: lane holds 8 k-contiguous elems at k = ks*32 + kg*8 + j
    s16x8 ah[4], al[4];
#pragma unroll
    for (int ks = 0; ks < 4; ++ks) {
        const float* ap = agg_in + (unsigned)arow * 128u + ks * 32 + kg * 8;
        const float* xp = x      + (unsigned)arow * 128u + ks * 32 + kg * 8;
        float4 a0 = *(const float4*)ap;
        float4 a1 = *(const float4*)(ap + 4);
        float4 x0 = *(const float4*)xp;
        float4 x1 = *(const float4*)(xp + 4);
        float v[8] = {a0.x + x0.x * di2, a0.y + x0.y * di2,
                      a0.z + x0.z * di2, a0.w + x0.w * di2,
                      a1.x + x1.x * di2, a1.y + x1.y * di2,
                      a1.z + x1.z * di2, a1.w + x1.w * di2};
        s16x8 h, l;
#pragma unroll
        for (int j = 0; j < 8; ++j) {
            unsigned short hb = f2bf(v[j]);
            h[j] = (short)hb;
            l[j] = (short)f2bf(v[j] - __uint_as_float((unsigned)hb << 16));
        }
        ah[ks] = h; al[ks] = l;
    }

#pragma unroll
    for (int ct = 0; ct < 8; ++ct) {
        f32x4 acc = {0.f, 0.f, 0.f, 0.f};
#pragma unroll
        for (int ks = 0; ks < 4; ++ks) {
            const int fo = ((ct * 4 + ks) * 64 + lane) * 8;
            s16x8 bh = *(const s16x8*)&wf_hi[fo];   // L2-resident global tables
            s16x8 bl = *(const s16x8*)&wf_lo[fo];
            acc = __builtin_amdgcn_mfma_f32_16x16x32_bf16(ah[ks], bh, acc, 0, 0, 0);
            acc = __builtin_amdgcn_mfma_f32_16x16x32_bf16(ah[ks], bl, acc, 0, 0, 0);
            acc = __builtin_amdgcn_mfma_f32_16x16x32_bf16(al[ks], bh, acc, 0, 0, 0);
        }
        // C/D layout (m89-verified): col = lane&15, row = (lane>>4)*4 + reg
        const int col = ct * 16 + mrow;
        const float bv = bias[col];
#pragma unroll
        for (int v = 0; v < 4; ++v) {
            const int row = r0 + kg * 4 + v;
            if (row < N_NODES) {
                float o = fmaxf(acc[v] + bv, 0.f) + x[(unsigned)row * 128u + col];
                out[(unsigned)row * 128u + col] = o;
            }
        }
    }
}

// ============================ legacy vector final (fallback paths) ============

__global__ __launch_bounds__(256) void final_kernel(const float* __restrict__ agg_in,
                                                    const float* __restrict__ x,
                                                    const float* __restrict__ bias,
                                                    const float* __restrict__ dinv,
                                                    const float* __restrict__ Wt,
                                                    float* __restrict__ out) {
    __shared__ float sh_wt[16384];
    const int tid = threadIdx.x;
    {
        const float4* s4 = (const float4*)Wt;
        float4* d4 = (float4*)sh_wt;
#pragma unroll
        for (int i = 0; i < 16; ++i) d4[i * 256 + tid] = s4[i * 256 + tid];
    }
    __syncthreads();

    const int wave = tid >> 6;
    const int lane = tid & 63;
    const int rowbase = blockIdx.x * 32 + wave * 8;

    float areg[16];
#pragma unroll
    for (int r = 0; r < 8; ++r) {
        int row = rowbase + r;
        float di = dinv[row];
        float di2 = di * di;
        int base = row * 128;
        areg[2 * r]     = agg_in[base + lane]      + x[base + lane]      * di2;
        areg[2 * r + 1] = agg_in[base + 64 + lane] + x[base + 64 + lane] * di2;
    }

    float acc0[8], acc1[8];
#pragma unroll
    for (int r = 0; r < 8; ++r) { acc0[r] = 0.f; acc1[r] = 0.f; }

    const float2* wt2 = (const float2*)sh_wt;

#pragma unroll
    for (int kh = 0; kh < 2; ++kh) {
#pragma unroll 16
        for (int kk = 0; kk < 64; ++kk) {
            int k = kh * 64 + kk;
            float2 w = wt2[k * 64 + lane];
#pragma unroll
            for (int r = 0; r < 8; ++r) {
                float ak = __uint_as_float(
                    __builtin_amdgcn_readlane(__float_as_uint(areg[2 * r + kh]), kk));
                acc0[r] = fmaf(ak, w.x, acc0[r]);
                acc1[r] = fmaf(ak, w.y, acc1[r]);
            }
        }
    }

    float2 b = ((const float2*)bias)[lane];
#pragma unroll
    for (int r = 0; r < 8; ++r) {
        int row = rowbase + r;
        float2 xr = ((const float2*)x)[row * 64 + lane];
        float v0 = fmaxf(acc0[r] + b.x, 0.f) + xr.x;
        float v1 = fmaxf(acc1[r] + b.y, 0.f) + xr.y;
        ((float2*)out)[row * 64 + lane] = make_float2(v0, v1);
    }
}

// ===============================================================================

extern "C" void kernel_launch(void* const* d_in, const int* in_sizes, int n_in,
                              void* d_out, int out_size, void* d_ws, size_t ws_size,
                              hipStream_t stream) {
    const float* x    = (const float*)d_in[0];
    const float* W    = (const float*)d_in[1];
    const float* bias = (const float*)d_in[2];
    const float* ew   = (const float*)d_in[3];
    const int*   ei   = (const int*)d_in[4];
    float* out = (float*)d_out;
    char* ws = (char*)d_ws;

    // ---------- primary layout (hierarchical partition) ----------
    // xh bf16[N*128]       [0, 25600000)
    // Wfrag hi/lo ushort   [25600000, 25665536)
    // dinv f32[N]          [25665536, 26065536)
    // row_start int[N]     [26065536, 26465536)
    // row_cnt int[N]       [26465536, 26865536)
    // fill_c int[98]       [26865536, ...) contiguous with fill_f int[1568]
    // edc u64[98*36864]    [26872256, 55773632)
    // edf u64[1568*2560]   [55773632, 87886272)
    unsigned short* xhA  = (unsigned short*)ws;
    ushort* wfhi     = (ushort*)(ws + 25600000);
    ushort* wflo     = wfhi + 16384;
    float* dinvA     = (float*)(ws + 25665536);
    int*   row_start = (int*)  (ws + 26065536);
    int*   row_cnt   = (int*)  (ws + 26465536);
    int*   fill_c    = (int*)  (ws + 26865536);
    int*   fill_f    = fill_c + NB_C;
    unsigned long long* edc = (unsigned long long*)(ws + 26872256);
    unsigned long long* edf = (unsigned long long*)(ws + 55773632);
    const size_t WS_PART = 87886272ull;

    // ---------- fallback layout (round-3 bucket) ----------
    unsigned long long* packed = (unsigned long long*)ws;
    float* dinvB = (float*)(ws + 800000);
    float* WtB   = (float*)(ws + 1200000);
    int2*  edB   = (int2*)(ws + 1265536);
    const size_t WS_BUCKET = 1265536ull + (size_t)N_NODES * CAP * 8ull;   // ~78.1 MB

    if (ws_size >= WS_PART) {
        prep_kernel<<<71, 256, 0, stream>>>(W, wfhi, wflo, fill_c);
        partA1_kernel<<<(N_EDGES + 4095) / 4096, 256, 0, stream>>>(ei, ew, fill_c, edc);
        partA2_kernel<<<NB_C * 9, 256, 0, stream>>>(fill_c, edc, fill_f, edf);
        partB_kernel<<<NB_F, 256, 0, stream>>>(fill_f, edf, dinvA, row_start, row_cnt,
                                               (const float4*)x, (ushort4*)xhA);
        gatherc_kernel<<<N_NODES / 4, 256, 0, stream>>>(row_start, row_cnt, edf, dinvA,
                                                        (const unsigned*)xhA, (float2*)out);
        final_mfma_kernel<<<(N_NODES + 63) / 64, 256, 0, stream>>>(out, x, bias, dinvA,
                                                                   wfhi, wflo, out);
    } else if (ws_size >= WS_BUCKET) {
        zero_u64_kernel<<<(N_NODES + 255) / 256, 256, 0, stream>>>(packed, N_NODES);
        wt_kernel<<<64, 256, 0, stream>>>(W, WtB);
        bucket_f32_kernel<<<N_EDGES / 256, 256, 0, stream>>>(ei, ew, packed, edB);
        dinv_packed_kernel<<<(N_NODES + 255) / 256, 256, 0, stream>>>(packed, dinvB);
        gatherb_f32_kernel<<<N_NODES / 4, 256, 0, stream>>>(packed, edB, dinvB,
                                                            (const float2*)x, (float2*)out);
        final_kernel<<<N_NODES / 32, 256, 0, stream>>>(out, x, bias, dinvB, WtB, out);
    } else {
        float* deg   = (float*)(ws);
        float* Wt    = (float*)(ws + 400000);
        int*   count = (int*)  (ws + 465536);
        zero_f_kernel<<<(N_NODES + 255) / 256, 256, 0, stream>>>(deg, N_NODES);
        zero_i_kernel<<<(N_NODES + 255) / 256, 256, 0, stream>>>(count, N_NODES);
        wt_kernel<<<64, 256, 0, stream>>>(W, Wt);
        zero_f4_kernel<<<(N_NODES * DIM / 4) / 256, 256, 0, stream>>>((float4*)out,
                                                                      N_NODES * DIM / 4);
        count_deg_kernel<<<N_EDGES / 256, 256, 0, stream>>>(ei, ew, count, deg);
        dinv_kernel<<<(N_NODES + 255) / 256, 256, 0, stream>>>(deg);
        scatter_kernel<<<(N_EDGES / 256) * 32, 256, 0, stream>>>(ei, ew, deg,
                                                                 (const float4*)x, out);
        final_kernel<<<N_NODES / 32, 256, 0, stream>>>(out, x, bias, deg, Wt, out);
    }
}